// Round 16
// baseline (189.783 us; speedup 1.0000x reference)
//
#include <hip/hip_runtime.h>

// HierarchicalTimeAttention  B=4, T=4096, H=1024, D=4
// R16: register-pipelined kvr. All prior structures serialized
// {ds_read -> barrier -> MFMA(same frags)} per phase (~0.049us/MFMA const
// across R8/R12/R13). Now each MFMA consumes frags read ONE PHASE EARLIER:
// aR double-buffered across tiles (read t-1 P3), bv/br read 1 phase ahead,
// bk single-set. Staging: P1 issues Bv,Br(t+1); P2 issues A,Bk(t+2) into
// cur; waits vmcnt(8)@P2end, vmcnt(4)@P3end (4-6 phase issue-to-drain,
// never 0 in loop). gemm_o + small kernels = R15 verbatim.
// R15: 175.4us = kvr 112.5 (38% Mfma) + gemm_o 51 + small 12.
#define B_ 4
#define T_ 4096
#define H_ 1024
#define D_ 4
#define M_ (B_ * T_)          // 16384
#define OUT_MAIN (M_ * H_)    // 16,777,216 (f32 elements)

#define WS_BUF  0UL           // bf16 [M][H]: o   (32MB)
#define WS_WK   33554432UL    // bf16 Wk,Wv,Wr,Wo contiguous [4][H][H] (8MB)
#define WS_LGW  41943040UL    // f32 softmax weights [M][4] (256KB)
#define WS_DEC  42205184UL    // f32 decayed_state0 [B][D][H] (64KB)

typedef __bf16 bf16x8 __attribute__((ext_vector_type(8)));
typedef unsigned short u16x4 __attribute__((ext_vector_type(4)));
typedef float f32x4 __attribute__((ext_vector_type(4)));

__device__ __forceinline__ float b2f(unsigned short u) {
    union { unsigned int i; float f; } c;
    c.i = ((unsigned int)u) << 16;
    return c.f;
}
__device__ __forceinline__ unsigned short f2b(float f) {
    union { float f; unsigned int i; } c;
    c.f = f;
    unsigned int x = c.i;
    unsigned int r = (x + 0x7FFFu + ((x >> 16) & 1u)) >> 16;  // RNE
    return (unsigned short)r;
}

#define BAR()  asm volatile("s_barrier" ::: "memory")
#define GLLDS(gsrc, ldst)                                                     \
    __builtin_amdgcn_global_load_lds(                                         \
        (const __attribute__((address_space(1))) unsigned int*)(gsrc),        \
        (__attribute__((address_space(3))) unsigned int*)(ldst), 16, 0, 0)

// ---------------------------------------------------------------------------
__global__ __launch_bounds__(256) void cvtw_k(
    const float* __restrict__ s0, const float* __restrict__ s1,
    const float* __restrict__ s2, const float* __restrict__ s3,
    unsigned short* __restrict__ d)
{
    const int w = blockIdx.y;
    const float* s = (w == 0) ? s0 : (w == 1) ? s1 : (w == 2) ? s2 : s3;
    const int i = blockIdx.x * 256 + threadIdx.x;
    const f32x4 v = ((const f32x4*)s)[i];
    u16x4 o;
    o[0] = f2b(v[0]); o[1] = f2b(v[1]); o[2] = f2b(v[2]); o[3] = f2b(v[3]);
    ((u16x4*)(d + (size_t)w * (H_ * H_)))[i] = o;
}

// ---------------------------------------------------------------------------
__global__ __launch_bounds__(256) void logcvt_k(
    const float* __restrict__ X, const float* __restrict__ Wl,
    const float* __restrict__ bl, float* __restrict__ lgw,
    unsigned short* __restrict__ xb)
{
    const int wid  = threadIdx.x >> 6;
    const int lane = threadIdx.x & 63;
    const int row  = blockIdx.x * 4 + wid;
    const float* xp = X + (size_t)row * H_;
    unsigned short* xo = xb + (size_t)row * H_;

    float acc[D_] = {0.f, 0.f, 0.f, 0.f};
    for (int h = lane * 4; h < H_; h += 256) {
        const f32x4 xv = *(const f32x4*)(xp + h);
        u16x4 xc;
        xc[0] = f2b(xv[0]); xc[1] = f2b(xv[1]);
        xc[2] = f2b(xv[2]); xc[3] = f2b(xv[3]);
        *(u16x4*)(xo + h) = xc;
#pragma unroll
        for (int d = 0; d < D_; ++d) {
            const f32x4 wv = *(const f32x4*)(Wl + d * H_ + h);
            acc[d] += xv[0] * wv[0] + xv[1] * wv[1] + xv[2] * wv[2] + xv[3] * wv[3];
        }
    }
#pragma unroll
    for (int off = 32; off; off >>= 1)
#pragma unroll
        for (int d = 0; d < D_; ++d) acc[d] += __shfl_xor(acc[d], off, 64);

    if (lane == 0) {
        float l[D_];
#pragma unroll
        for (int d = 0; d < D_; ++d) l[d] = acc[d] + bl[d];
        const float mx = fmaxf(fmaxf(l[0], l[1]), fmaxf(l[2], l[3]));
        float e[D_], s = 0.f;
#pragma unroll
        for (int d = 0; d < D_; ++d) { e[d] = __expf(l[d] - mx); s += e[d]; }
        const float inv = 1.0f / s;
        f32x4 o;
#pragma unroll
        for (int d = 0; d < D_; ++d) o[d] = e[d] * inv;
        *(f32x4*)(lgw + (size_t)row * 4) = o;
    }
}

// ---------------------------------------------------------------------------
__global__ void decstate_k(const float* __restrict__ state,
                           const float* __restrict__ tdm,
                           float* __restrict__ dec)
{
    const int i = blockIdx.x * blockDim.x + threadIdx.x;
    if (i >= B_ * D_ * H_) return;
    const int dh = i & (D_ * H_ - 1);
    dec[i] = state[i] * __expf(-__expf(tdm[dh]));
}

// ---------------------------------------------------------------------------
__global__ __launch_bounds__(256) void newstate_k(
    const float* __restrict__ X, const float* __restrict__ Wk,
    const float* __restrict__ Wv, const float* __restrict__ dec,
    float* __restrict__ out2)
{
    const int wid  = threadIdx.x >> 6;
    const int lane = threadIdx.x & 63;
    const int row  = blockIdx.x * 4 + wid;   // 0..B*H-1
    const int b    = row >> 10;
    const int h    = row & (H_ - 1);
    const float* xp = X + ((size_t)(b * T_ + (T_ - 1))) * H_;

    float ak = 0.f, av = 0.f;
    for (int j = lane * 4; j < H_; j += 256) {
        const f32x4 xv = *(const f32x4*)(xp + j);
        const f32x4 wk = *(const f32x4*)(Wk + (size_t)h * H_ + j);
        const f32x4 wv = *(const f32x4*)(Wv + (size_t)h * H_ + j);
        ak += xv[0]*wk[0] + xv[1]*wk[1] + xv[2]*wk[2] + xv[3]*wk[3];
        av += xv[0]*wv[0] + xv[1]*wv[1] + xv[2]*wv[2] + xv[3]*wv[3];
    }
#pragma unroll
    for (int off = 32; off; off >>= 1) {
        ak += __shfl_xor(ak, off, 64);
        av += __shfl_xor(av, off, 64);
    }
    if (lane == 0) {
        const float kv = ak * av;
#pragma unroll
        for (int d = 0; d < D_; ++d)
            out2[(size_t)(b * D_ + d) * H_ + h] = dec[(b * D_ + d) * H_ + h] + kv;
    }
}

// ---------------------------------------------------------------------------
// FUSED KVR GEMM + o-epilogue, REGISTER-PIPELINED (see file header).
// Geometry/swizzle/epilogue identical to R13/R15 (XCD swizzle kept).
// ---------------------------------------------------------------------------
__global__ __launch_bounds__(512, 2) void gemm_kvr(
    const unsigned short* __restrict__ A,
    const unsigned short* __restrict__ Wk,
    const unsigned short* __restrict__ Wv,
    const unsigned short* __restrict__ Wr,
    unsigned short* __restrict__ Co,
    const float* __restrict__ lgw,
    const float* __restrict__ dec)
{
    __shared__ __align__(16) unsigned short As [2 * 8192];   // [2][128][64]
    __shared__ __align__(16) unsigned short Bks[2 * 8192];
    __shared__ __align__(16) unsigned short Bvs[2 * 8192];
    __shared__ __align__(16) unsigned short Brs[2 * 8192];

    const int tid  = threadIdx.x;
    const int wid  = tid >> 6;
    const int lane = tid & 63;
    const int l15  = lane & 15;
    const int q    = lane >> 4;
    const int wrow = wid >> 2;        // 0..1
    const int wcol = wid & 3;         // 0..3

    // XCD-aware swizzle (R15): xcd owns 16 contiguous brow-bands.
    const int lin  = blockIdx.y * 8 + blockIdx.x;
    const int xcd  = lin & 7;
    const int slot = lin >> 3;                // 0..127
    const int brow = (xcd * 16 + (slot >> 3)) * 128;
    const int bcol = (slot & 7) * 128;

    const int g0row = tid >> 3, g0cg = (tid & 7) ^ (g0row & 7);
    const int g1row = 64 + g0row, g1cg = (tid & 7) ^ (g1row & 7);
    const int offA0 = (brow + g0row) * 1024 + g0cg * 8;
    const int offA1 = (brow + g1row) * 1024 + g1cg * 8;
    const int offB0 = (bcol + g0row) * 1024 + g0cg * 8;
    const int offB1 = (bcol + g1row) * 1024 + g1cg * 8;
    const int dst0 = tid * 8;
    const int dst1 = 4096 + tid * 8;

    int gx[2];
#pragma unroll
    for (int ks = 0; ks < 2; ++ks) gx[ks] = ((ks * 4 + q) ^ (l15 & 7)) * 8;
    int aB[4], bB[2];
#pragma unroll
    for (int mi = 0; mi < 4; ++mi) aB[mi] = (wrow * 64 + mi * 16 + l15) * 64;
#pragma unroll
    for (int ni = 0; ni < 2; ++ni) bB[ni] = (wcol * 32 + ni * 16 + l15) * 64;

    f32x4 accK[4][2], accV[4][2], accR[4][2];
#pragma unroll
    for (int i = 0; i < 4; ++i)
#pragma unroll
        for (int j = 0; j < 2; ++j) {
            accK[i][j] = (f32x4){0.f, 0.f, 0.f, 0.f};
            accV[i][j] = (f32x4){0.f, 0.f, 0.f, 0.f};
            accR[i][j] = (f32x4){0.f, 0.f, 0.f, 0.f};
        }

    // register fragments: aR double-buffered (cross-tile), bk single
    // (WAR-safe: last use P1, re-read P3), bv/br read 1 phase ahead in-tile
    bf16x8 aR0[4][2], aR1[4][2], bk[2][2], bv[2][2], br[2][2];

#define SG_A(bo, tau)  do { GLLDS(A  + offA0 + (tau) * 64, As  + (bo) + dst0); \
                            GLLDS(A  + offA1 + (tau) * 64, As  + (bo) + dst1); } while (0)
#define SG_BK(bo, tau) do { GLLDS(Wk + offB0 + (tau) * 64, Bks + (bo) + dst0); \
                            GLLDS(Wk + offB1 + (tau) * 64, Bks + (bo) + dst1); } while (0)
#define SG_BV(bo, tau) do { GLLDS(Wv + offB0 + (tau) * 64, Bvs + (bo) + dst0); \
                            GLLDS(Wv + offB1 + (tau) * 64, Bvs + (bo) + dst1); } while (0)
#define SG_BR(bo, tau) do { GLLDS(Wr + offB0 + (tau) * 64, Brs + (bo) + dst0); \
                            GLLDS(Wr + offB1 + (tau) * 64, Brs + (bo) + dst1); } while (0)
#define RD_AALL(DST, CUR)                                                     \
    _Pragma("unroll") for (int mi = 0; mi < 4; ++mi)                          \
    _Pragma("unroll") for (int ks = 0; ks < 2; ++ks)                          \
        DST[mi][ks] = *(const bf16x8*)&As[(CUR) + aB[mi] + gx[ks]];
#define RDB2(DST, ARR, CUR)                                                   \
    _Pragma("unroll") for (int nj = 0; nj < 2; ++nj)                          \
    _Pragma("unroll") for (int ks = 0; ks < 2; ++ks)                          \
        DST[nj][ks] = *(const bf16x8*)&ARR[(CUR) + bB[nj] + gx[ks]];
#define MFMA16A(ACC, AARR, BARR)                                              \
    __builtin_amdgcn_s_setprio(1);                                            \
    _Pragma("unroll") for (int mi = 0; mi < 4; ++mi)                          \
    _Pragma("unroll") for (int nj = 0; nj < 2; ++nj)                          \
    _Pragma("unroll") for (int ks = 0; ks < 2; ++ks)                          \
        ACC[mi][nj] = __builtin_amdgcn_mfma_f32_16x16x32_bf16(                \
            AARR[mi][ks], BARR[nj][ks], ACC[mi][nj], 0, 0, 0);                \
    __builtin_amdgcn_s_setprio(0);

// Steady tile T (0..13): ARC = frags for tile T (read at T-1 P3),
// ARN = destination for tile T+1 frags.
#define TILE(T, CUR, NXT, ARC, ARN)                                           \
    /* P1: rd bv(T); stage Bv,Br(T+1); MFMA-K on pre-read frags */            \
    RDB2(bv, Bvs, CUR);                                                       \
    SG_BV(NXT, (T) + 1); SG_BR(NXT, (T) + 1);                                 \
    BAR(); MFMA16A(accK, ARC, bk); BAR();                                     \
    /* P2: rd br(T); stage A,Bk(T+2) into CUR (A-LDS reads done T-1 P3) */    \
    RDB2(br, Brs, CUR);                                                       \
    SG_A(CUR, (T) + 2); SG_BK(CUR, (T) + 2);                                  \
    BAR(); MFMA16A(accV, ARC, bv);                                            \
    asm volatile("s_waitcnt vmcnt(8)" ::: "memory");  /* A,Bk(T+1) landed */  \
    BAR();                                                                    \
    /* P3: rd aR,bk(T+1) from NXT; MFMA-R */                                  \
    RD_AALL(ARN, NXT); RDB2(bk, Bks, NXT);                                    \
    BAR(); MFMA16A(accR, ARC, br);                                            \
    asm volatile("s_waitcnt vmcnt(4)" ::: "memory");  /* Bv,Br(T+1) landed */ \
    BAR();

    // --- prologue: tile0 full + A,Bk(1); pre-read tile0 frags
    SG_A(0, 0); SG_BK(0, 0); SG_BV(0, 0); SG_BR(0, 0);
    SG_A(8192, 1); SG_BK(8192, 1);
    asm volatile("s_waitcnt vmcnt(4)" ::: "memory");   // tile0's 8 landed
    BAR();
    RD_AALL(aR0, 0); RDB2(bk, Bks, 0);

#pragma unroll 1
    for (int t = 0; t < 14; t += 2) {
        TILE(t,     0,    8192, aR0, aR1)
        TILE(t + 1, 8192, 0,    aR1, aR0)
    }
    // --- t=14 (even): no A(16); tail waits vmcnt(4) then vmcnt(0)
    RDB2(bv, Bvs, 0);
    SG_BV(8192, 15); SG_BR(8192, 15);
    BAR(); MFMA16A(accK, aR0, bk); BAR();
    RDB2(br, Brs, 0);
    BAR(); MFMA16A(accV, aR0, bv);
    asm volatile("s_waitcnt vmcnt(4)" ::: "memory");   // A,Bk(15) landed
    BAR();
    RD_AALL(aR1, 8192); RDB2(bk, Bks, 8192);
    BAR(); MFMA16A(accR, aR0, br);
    asm volatile("s_waitcnt vmcnt(0)" ::: "memory");   // Bv,Br(15) landed
    BAR();
    // --- t=15: fully resident, no stages/barriers
    RDB2(bv, Bvs, 8192);
    MFMA16A(accK, aR1, bk);
    RDB2(br, Brs, 8192);
    MFMA16A(accV, aR1, bv);
    MFMA16A(accR, aR1, br);

#undef SG_A
#undef SG_BK
#undef SG_BV
#undef SG_BR
#undef RD_AALL
#undef RDB2
#undef MFMA16A
#undef TILE

    // --- epilogue (R13 verbatim): o = sigmoid(accR)*(lw.dec + wsum*kv)
    const int orow0 = brow + wrow * 64;
    const int ocol0 = bcol + wcol * 32;
    const int rbase = q * 4;
    const int b = brow >> 12;
    float dcol[2][4];
#pragma unroll
    for (int ni = 0; ni < 2; ++ni)
#pragma unroll
        for (int d = 0; d < 4; ++d)
            dcol[ni][d] = dec[b * (D_ * H_) + d * H_ + (ocol0 + ni * 16 + l15)];
#pragma unroll
    for (int mi = 0; mi < 4; ++mi)
#pragma unroll
        for (int j = 0; j < 4; ++j) {
            const int r = orow0 + mi * 16 + rbase + j;
            const f32x4 lw = *(const f32x4*)(lgw + (size_t)r * 4);
            const float wsum = lw[0] + lw[1] + lw[2] + lw[3];
#pragma unroll
            for (int ni = 0; ni < 2; ++ni) {
                const size_t idx = (size_t)r * 1024 + (ocol0 + ni * 16 + l15);
                const float kvf = b2f(f2b(accV[mi][ni][j] * b2f(f2b(accK[mi][ni][j]))));
                const float rv  = 1.0f / (1.0f + __expf(-accR[mi][ni][j]));
                const float w   = lw[0] * dcol[ni][0] + lw[1] * dcol[ni][1]
                                + lw[2] * dcol[ni][2] + lw[3] * dcol[ni][3]
                                + wsum * kvf;
                Co[idx] = f2b(rv * w);
            }
        }
}

// ---------------------------------------------------------------------------
// o-GEMM (R8 structure verbatim, 51us): out = f32(o @ Wo^T)
// ---------------------------------------------------------------------------
__global__ __launch_bounds__(512, 2) void gemm_o(
    const unsigned short* __restrict__ A,
    const unsigned short* __restrict__ Wt,
    float* __restrict__ outf)
{
    __shared__ __align__(16) unsigned short As[2 * 256 * 64];
    __shared__ __align__(16) unsigned short Bs[2 * 256 * 64];

    const int tid  = threadIdx.x;
    const int wid  = tid >> 6;
    const int lane = tid & 63;
    const int l15  = lane & 15;
    const int l7   = lane & 7;
    const int wrow = wid >> 2;
    const int wcol = wid & 3;
    const int brow = blockIdx.x * 256;
    const int bcol = blockIdx.y * 256;

    int offA[4], offB[4], dst[4];
#pragma unroll
    for (int i = 0; i < 4; ++i) {
        const int G   = i * 512 + tid;
        const int row = G >> 3;
        const int cg  = (G & 7) ^ (row & 7);
        offA[i] = (brow + row) * 1024 + cg * 8;
        offB[i] = (bcol + row) * 1024 + cg * 8;
        dst[i]  = G * 8;
    }

    int aB[8], bB[4], gx[2];
#pragma unroll
    for (int ks = 0; ks < 2; ++ks) gx[ks] = ((ks * 4 + (lane >> 4)) ^ l7) * 8;
#pragma unroll
    for (int mi = 0; mi < 8; ++mi) aB[mi] = (wrow * 128 + mi * 16 + l15) * 64;
#pragma unroll
    for (int ni = 0; ni < 4; ++ni) bB[ni] = (wcol * 64 + ni * 16 + l15) * 64;

    f32x4 acc[8][4];
#pragma unroll
    for (int i = 0; i < 8; ++i)
#pragma unroll
        for (int j = 0; j < 4; ++j)
            acc[i][j] = (f32x4){0.f, 0.f, 0.f, 0.f};

#pragma unroll
    for (int i = 0; i < 4; ++i) {
        GLLDS(A  + offA[i], As + dst[i]);
        GLLDS(Wt + offB[i], Bs + dst[i]);
    }
    asm volatile("s_waitcnt vmcnt(0)" ::: "memory");
    BAR();

#pragma unroll 1
    for (int t = 0; t < 16; ++t) {
        const int cur = (t & 1) * 16384;
        const int nxt = 16384 - cur;
        const int kk  = (t + 1) * 64;
        const bool st = (t < 15);
        bf16x8 aR[4][2], bR[4][2];

#pragma unroll
        for (int mi = 0; mi < 4; ++mi)
#pragma unroll
            for (int ks = 0; ks < 2; ++ks)
                aR[mi][ks] = *(const bf16x8*)&As[cur + aB[mi] + gx[ks]];
#pragma unroll
        for (int ni = 0; ni < 2; ++ni)
#pragma unroll
            for (int ks = 0; ks < 2; ++ks)
                bR[ni][ks] = *(const bf16x8*)&Bs[cur + bB[ni] + gx[ks]];
        if (st) {
            GLLDS(A  + offA[0] + kk, As + nxt + dst[0]);
            GLLDS(A  + offA[1] + kk, As + nxt + dst[1]);
            GLLDS(Wt + offB[0] + kk, Bs + nxt + dst[0]);
        }
        BAR();
        __builtin_amdgcn_s_setprio(1);
#pragma unroll
        for (int mi = 0; mi < 4; ++mi)
#pragma unroll
            for (int ni = 0; ni < 2; ++ni)
#pragma unroll
                for (int ks = 0; ks < 2; ++ks)
                    acc[mi][ni] = __builtin_amdgcn_mfma_f32_16x16x32_bf16(
                        aR[mi][ks], bR[ni][ks], acc[mi][ni], 0, 0, 0);
        __builtin_amdgcn_s_setprio(0);
        BAR();

#pragma unroll
        for (int ni = 2; ni < 4; ++ni)
#pragma unroll
            for (int ks = 0; ks < 2; ++ks)
                bR[ni][ks] = *(const bf16x8*)&Bs[cur + bB[ni] + gx[ks]];
        if (st) {
            GLLDS(A  + offA[2] + kk, As + nxt + dst[2]);
            GLLDS(A  + offA[3] + kk, As + nxt + dst[3]);
            GLLDS(Wt + offB[1] + kk, Bs + nxt + dst[1]);
        }
        BAR();
        __builtin_amdgcn_s_setprio(1);
#pragma unroll
        for (int mi = 0; mi < 4; ++mi)
#pragma unroll
            for (int ni = 2; ni < 4; ++ni)
#pragma unroll
                for (int ks = 0; ks < 2; ++ks)
                    acc[mi][ni] = __builtin_amdgcn_mfma_f32_16x16x32_bf16(
                        aR[mi][ks], bR[ni][ks], acc[mi][ni], 0, 0, 0);
        __builtin_amdgcn_s_setprio(0);
        BAR();

#pragma unroll
        for (int mi = 0; mi < 4; ++mi)
#pragma unroll
            for (int ks = 0; ks < 2; ++ks)
                aR[mi][ks] = *(const bf16x8*)&As[cur + aB[4 + mi] + gx[ks]];
        if (st) {
            GLLDS(Wt + offB[2] + kk, Bs + nxt + dst[2]);
            GLLDS(Wt + offB[3] + kk, Bs + nxt + dst[3]);
        }
        BAR();
        __builtin_amdgcn_s_setprio(1);
#pragma unroll
        for (int mi = 0; mi < 4; ++mi)
#pragma unroll
            for (int ni = 2; ni < 4; ++ni)
#pragma unroll
                for (int ks = 0; ks < 2; ++ks)
                    acc[4 + mi][ni] = __builtin_amdgcn_mfma_f32_16x16x32_bf16(
                        aR[mi][ks], bR[ni][ks], acc[4 + mi][ni], 0, 0, 0);
        __builtin_amdgcn_s_setprio(0);
        BAR();

        __builtin_amdgcn_s_setprio(1);
#pragma unroll
        for (int mi = 0; mi < 4; ++mi)
#pragma unroll
            for (int ni = 0; ni < 2; ++ni)
#pragma unroll
                for (int ks = 0; ks < 2; ++ks)
                    acc[4 + mi][ni] = __builtin_amdgcn_mfma_f32_16x16x32_bf16(
                        aR[mi][ks], bR[ni][ks], acc[4 + mi][ni], 0, 0, 0);
        __builtin_amdgcn_s_setprio(0);
        asm volatile("s_waitcnt vmcnt(0)" ::: "memory");
        BAR();
    }

    const int orow0 = brow + wrow * 128;
    const int ocol0 = bcol + wcol * 64;
    const int rbase = (lane >> 4) * 4;
#pragma unroll
    for (int mi = 0; mi < 8; ++mi)
#pragma unroll
        for (int j = 0; j < 4; ++j) {
            const size_t r = (size_t)(orow0 + mi * 16 + rbase + j);
#pragma unroll
            for (int ni = 0; ni < 4; ++ni)
                outf[r * 1024 + (ocol0 + ni * 16 + l15)] = acc[mi][ni][j];
        }
}

// ---------------------------------------------------------------------------
extern "C" void kernel_launch(void* const* d_in, const int* in_sizes, int n_in,
                              void* d_out, int out_size, void* d_ws, size_t ws_size,
                              hipStream_t stream)
{
    const float* x   = (const float*)d_in[0];
    const float* st  = (const float*)d_in[1];
    const float* tdm = (const float*)d_in[2];
    const float* Wl  = (const float*)d_in[3];
    const float* bl  = (const float*)d_in[4];
    const float* Wv  = (const float*)d_in[5];
    const float* Wk  = (const float*)d_in[6];
    const float* Wr  = (const float*)d_in[7];
    const float* Wo  = (const float*)d_in[8];
    float* out = (float*)d_out;                    // f32 output

    char* ws = (char*)d_ws;
    unsigned short* buf  = (unsigned short*)(ws + WS_BUF);   // o
    unsigned short* wk_b = (unsigned short*)(ws + WS_WK);    // [4][H][H]: k,v,r,o
    unsigned short* wv_b = wk_b + 1 * (H_ * H_);
    unsigned short* wr_b = wk_b + 2 * (H_ * H_);
    unsigned short* wo_b = wk_b + 3 * (H_ * H_);
    float* lgw = (float*)(ws + WS_LGW);
    float* dec = (float*)(ws + WS_DEC);

    // bf16 x scratch inside d_out's f32 output-0 region; final GEMM
    // fully overwrites it afterwards.
    unsigned short* xb = (unsigned short*)out;

    // small kernels
    decstate_k<<<(B_ * D_ * H_ + 255) / 256, 256, 0, stream>>>(st, tdm, dec);
    logcvt_k<<<M_ / 4, 256, 0, stream>>>(x, Wl, bl, lgw, xb);
    newstate_k<<<(B_ * H_) / 4, 256, 0, stream>>>(x, Wk, Wv, dec, out + OUT_MAIN);
    cvtw_k<<<dim3(1024, 4), 256, 0, stream>>>(Wk, Wv, Wr, Wo, wk_b);

    // buf = o = sigmoid(x@Wr^T) * (lw.dec + wsum*(x@Wk^T * x@Wv^T))
    gemm_kvr<<<dim3(8, 128), 512, 0, stream>>>(
        xb, wk_b, wv_b, wr_b, buf, lgw, dec);

    // out = f32(o @ Wo^T)
    gemm_o<<<dim3(M_ / 256, H_ / 256), 512, 0, stream>>>(buf, wo_b, out);
}

// Round 17
// 181.969 us; speedup vs baseline: 1.0429x; 1.0429x over previous
//
#include <hip/hip_runtime.h>

// HierarchicalTimeAttention  B=4, T=4096, H=1024, D=4
// R17: kvr reverted to R15 (112.5us proven; R16 reg-pipeline regressed).
// gemm_o rebuilt as the single-B mirror of R12's 903-TF profile:
// 256x256 tile, 8 waves 64x128 (acc[4][8]=128 VGPR = R12's dual-acc), BK=64,
// 4 phases/tile x {4 ds_read + 16 MFMA}, aR read once/tile (reused 4x),
// stages {P1:Bh0(t+1), P2:Bh1(t+1), P3:A01(t+2)->cur, P4:A23(t+2)->cur},
// counted vmcnt(4) at tile end (A(t+2) stays in flight). R14's failure was
// 2 phases/tile (drain amortized over half the MFMA); this keeps 4.
#define B_ 4
#define T_ 4096
#define H_ 1024
#define D_ 4
#define M_ (B_ * T_)          // 16384
#define OUT_MAIN (M_ * H_)    // 16,777,216 (f32 elements)

#define WS_BUF  0UL           // bf16 [M][H]: o   (32MB)
#define WS_WK   33554432UL    // bf16 Wk,Wv,Wr,Wo contiguous [4][H][H] (8MB)
#define WS_LGW  41943040UL    // f32 softmax weights [M][4] (256KB)
#define WS_DEC  42205184UL    // f32 decayed_state0 [B][D][H] (64KB)

typedef __bf16 bf16x8 __attribute__((ext_vector_type(8)));
typedef unsigned short u16x4 __attribute__((ext_vector_type(4)));
typedef float f32x4 __attribute__((ext_vector_type(4)));

__device__ __forceinline__ float b2f(unsigned short u) {
    union { unsigned int i; float f; } c;
    c.i = ((unsigned int)u) << 16;
    return c.f;
}
__device__ __forceinline__ unsigned short f2b(float f) {
    union { float f; unsigned int i; } c;
    c.f = f;
    unsigned int x = c.i;
    unsigned int r = (x + 0x7FFFu + ((x >> 16) & 1u)) >> 16;  // RNE
    return (unsigned short)r;
}

#define BAR()  asm volatile("s_barrier" ::: "memory")
#define GLLDS(gsrc, ldst)                                                     \
    __builtin_amdgcn_global_load_lds(                                         \
        (const __attribute__((address_space(1))) unsigned int*)(gsrc),        \
        (__attribute__((address_space(3))) unsigned int*)(ldst), 16, 0, 0)

// ---------------------------------------------------------------------------
__global__ __launch_bounds__(256) void cvtw_k(
    const float* __restrict__ s0, const float* __restrict__ s1,
    const float* __restrict__ s2, const float* __restrict__ s3,
    unsigned short* __restrict__ d)
{
    const int w = blockIdx.y;
    const float* s = (w == 0) ? s0 : (w == 1) ? s1 : (w == 2) ? s2 : s3;
    const int i = blockIdx.x * 256 + threadIdx.x;
    const f32x4 v = ((const f32x4*)s)[i];
    u16x4 o;
    o[0] = f2b(v[0]); o[1] = f2b(v[1]); o[2] = f2b(v[2]); o[3] = f2b(v[3]);
    ((u16x4*)(d + (size_t)w * (H_ * H_)))[i] = o;
}

// ---------------------------------------------------------------------------
__global__ __launch_bounds__(256) void logcvt_k(
    const float* __restrict__ X, const float* __restrict__ Wl,
    const float* __restrict__ bl, float* __restrict__ lgw,
    unsigned short* __restrict__ xb)
{
    const int wid  = threadIdx.x >> 6;
    const int lane = threadIdx.x & 63;
    const int row  = blockIdx.x * 4 + wid;
    const float* xp = X + (size_t)row * H_;
    unsigned short* xo = xb + (size_t)row * H_;

    float acc[D_] = {0.f, 0.f, 0.f, 0.f};
    for (int h = lane * 4; h < H_; h += 256) {
        const f32x4 xv = *(const f32x4*)(xp + h);
        u16x4 xc;
        xc[0] = f2b(xv[0]); xc[1] = f2b(xv[1]);
        xc[2] = f2b(xv[2]); xc[3] = f2b(xv[3]);
        *(u16x4*)(xo + h) = xc;
#pragma unroll
        for (int d = 0; d < D_; ++d) {
            const f32x4 wv = *(const f32x4*)(Wl + d * H_ + h);
            acc[d] += xv[0] * wv[0] + xv[1] * wv[1] + xv[2] * wv[2] + xv[3] * wv[3];
        }
    }
#pragma unroll
    for (int off = 32; off; off >>= 1)
#pragma unroll
        for (int d = 0; d < D_; ++d) acc[d] += __shfl_xor(acc[d], off, 64);

    if (lane == 0) {
        float l[D_];
#pragma unroll
        for (int d = 0; d < D_; ++d) l[d] = acc[d] + bl[d];
        const float mx = fmaxf(fmaxf(l[0], l[1]), fmaxf(l[2], l[3]));
        float e[D_], s = 0.f;
#pragma unroll
        for (int d = 0; d < D_; ++d) { e[d] = __expf(l[d] - mx); s += e[d]; }
        const float inv = 1.0f / s;
        f32x4 o;
#pragma unroll
        for (int d = 0; d < D_; ++d) o[d] = e[d] * inv;
        *(f32x4*)(lgw + (size_t)row * 4) = o;
    }
}

// ---------------------------------------------------------------------------
__global__ void decstate_k(const float* __restrict__ state,
                           const float* __restrict__ tdm,
                           float* __restrict__ dec)
{
    const int i = blockIdx.x * blockDim.x + threadIdx.x;
    if (i >= B_ * D_ * H_) return;
    const int dh = i & (D_ * H_ - 1);
    dec[i] = state[i] * __expf(-__expf(tdm[dh]));
}

// ---------------------------------------------------------------------------
__global__ __launch_bounds__(256) void newstate_k(
    const float* __restrict__ X, const float* __restrict__ Wk,
    const float* __restrict__ Wv, const float* __restrict__ dec,
    float* __restrict__ out2)
{
    const int wid  = threadIdx.x >> 6;
    const int lane = threadIdx.x & 63;
    const int row  = blockIdx.x * 4 + wid;   // 0..B*H-1
    const int b    = row >> 10;
    const int h    = row & (H_ - 1);
    const float* xp = X + ((size_t)(b * T_ + (T_ - 1))) * H_;

    float ak = 0.f, av = 0.f;
    for (int j = lane * 4; j < H_; j += 256) {
        const f32x4 xv = *(const f32x4*)(xp + j);
        const f32x4 wk = *(const f32x4*)(Wk + (size_t)h * H_ + j);
        const f32x4 wv = *(const f32x4*)(Wv + (size_t)h * H_ + j);
        ak += xv[0]*wk[0] + xv[1]*wk[1] + xv[2]*wk[2] + xv[3]*wk[3];
        av += xv[0]*wv[0] + xv[1]*wv[1] + xv[2]*wv[2] + xv[3]*wv[3];
    }
#pragma unroll
    for (int off = 32; off; off >>= 1) {
        ak += __shfl_xor(ak, off, 64);
        av += __shfl_xor(av, off, 64);
    }
    if (lane == 0) {
        const float kv = ak * av;
#pragma unroll
        for (int d = 0; d < D_; ++d)
            out2[(size_t)(b * D_ + d) * H_ + h] = dec[(b * D_ + d) * H_ + h] + kv;
    }
}

// ---------------------------------------------------------------------------
// FUSED KVR GEMM + o-epilogue (R15 verbatim: 112.5us, 38% MfmaUtil).
// ---------------------------------------------------------------------------
__global__ __launch_bounds__(512, 2) void gemm_kvr(
    const unsigned short* __restrict__ A,
    const unsigned short* __restrict__ Wk,
    const unsigned short* __restrict__ Wv,
    const unsigned short* __restrict__ Wr,
    unsigned short* __restrict__ Co,
    const float* __restrict__ lgw,
    const float* __restrict__ dec)
{
    __shared__ __align__(16) unsigned short As [2 * 8192];   // [2][128][64]
    __shared__ __align__(16) unsigned short Bks[2 * 8192];
    __shared__ __align__(16) unsigned short Bvs[2 * 8192];
    __shared__ __align__(16) unsigned short Brs[2 * 8192];

    const int tid  = threadIdx.x;
    const int wid  = tid >> 6;
    const int lane = tid & 63;
    const int l15  = lane & 15;
    const int q    = lane >> 4;
    const int wrow = wid >> 2;        // 0..1
    const int wcol = wid & 3;         // 0..3

    const int lin  = blockIdx.y * 8 + blockIdx.x;
    const int xcd  = lin & 7;
    const int slot = lin >> 3;                // 0..127
    const int brow = (xcd * 16 + (slot >> 3)) * 128;
    const int bcol = (slot & 7) * 128;

    const int g0row = tid >> 3, g0cg = (tid & 7) ^ (g0row & 7);
    const int g1row = 64 + g0row, g1cg = (tid & 7) ^ (g1row & 7);
    const int offA0 = (brow + g0row) * 1024 + g0cg * 8;
    const int offA1 = (brow + g1row) * 1024 + g1cg * 8;
    const int offB0 = (bcol + g0row) * 1024 + g0cg * 8;
    const int offB1 = (bcol + g1row) * 1024 + g1cg * 8;
    const int dst0 = tid * 8;
    const int dst1 = 4096 + tid * 8;

    int gx[2];
#pragma unroll
    for (int ks = 0; ks < 2; ++ks) gx[ks] = ((ks * 4 + q) ^ (l15 & 7)) * 8;
    int aB[4], bB[2];
#pragma unroll
    for (int mi = 0; mi < 4; ++mi) aB[mi] = (wrow * 64 + mi * 16 + l15) * 64;
#pragma unroll
    for (int ni = 0; ni < 2; ++ni) bB[ni] = (wcol * 32 + ni * 16 + l15) * 64;

    f32x4 accK[4][2], accV[4][2], accR[4][2];
#pragma unroll
    for (int i = 0; i < 4; ++i)
#pragma unroll
        for (int j = 0; j < 2; ++j) {
            accK[i][j] = (f32x4){0.f, 0.f, 0.f, 0.f};
            accV[i][j] = (f32x4){0.f, 0.f, 0.f, 0.f};
            accR[i][j] = (f32x4){0.f, 0.f, 0.f, 0.f};
        }

#define SG_A(bo, tau)  do { GLLDS(A  + offA0 + (tau) * 64, As  + (bo) + dst0); \
                            GLLDS(A  + offA1 + (tau) * 64, As  + (bo) + dst1); } while (0)
#define SG_BK(bo, tau) do { GLLDS(Wk + offB0 + (tau) * 64, Bks + (bo) + dst0); \
                            GLLDS(Wk + offB1 + (tau) * 64, Bks + (bo) + dst1); } while (0)
#define SG_BV(bo, tau) do { GLLDS(Wv + offB0 + (tau) * 64, Bvs + (bo) + dst0); \
                            GLLDS(Wv + offB1 + (tau) * 64, Bvs + (bo) + dst1); } while (0)
#define SG_BR(bo, tau) do { GLLDS(Wr + offB0 + (tau) * 64, Brs + (bo) + dst0); \
                            GLLDS(Wr + offB1 + (tau) * 64, Brs + (bo) + dst1); } while (0)
#define RD_AALL(CUR)                                                          \
    _Pragma("unroll") for (int mi = 0; mi < 4; ++mi)                          \
    _Pragma("unroll") for (int ks = 0; ks < 2; ++ks)                          \
        aR[mi][ks] = *(const bf16x8*)&As[(CUR) + aB[mi] + gx[ks]];
#define RD_B(ARR, CUR)                                                        \
    _Pragma("unroll") for (int nj = 0; nj < 2; ++nj)                          \
    _Pragma("unroll") for (int ks = 0; ks < 2; ++ks)                          \
        bR[nj][ks] = *(const bf16x8*)&ARR[(CUR) + bB[nj] + gx[ks]];
#define MFMA16(ACC)                                                           \
    __builtin_amdgcn_s_setprio(1);                                            \
    _Pragma("unroll") for (int mi = 0; mi < 4; ++mi)                          \
    _Pragma("unroll") for (int nj = 0; nj < 2; ++nj)                          \
    _Pragma("unroll") for (int ks = 0; ks < 2; ++ks)                          \
        ACC[mi][nj] = __builtin_amdgcn_mfma_f32_16x16x32_bf16(                \
            aR[mi][ks], bR[nj][ks], ACC[mi][nj], 0, 0, 0);                    \
    __builtin_amdgcn_s_setprio(0);

    SG_A(0, 0); SG_BK(0, 0); SG_BV(0, 0); SG_BR(0, 0);
    asm volatile("s_waitcnt vmcnt(4)" ::: "memory");
    BAR();

#pragma unroll 1
    for (int t = 0; t < 15; ++t) {
        const int cur = (t & 1) << 13;
        const int nxt = cur ^ 8192;
        bf16x8 aR[4][2], bR[2][2];

        RD_AALL(cur); RD_B(Bks, cur);
        SG_A(nxt, t + 1); SG_BK(nxt, t + 1);
        BAR(); MFMA16(accK);
        asm volatile("s_waitcnt vmcnt(6)" ::: "memory");
        BAR();

        RD_B(Bvs, cur);
        SG_BV(nxt, t + 1);
        BAR(); MFMA16(accV);
        asm volatile("s_waitcnt vmcnt(6)" ::: "memory");
        BAR();

        RD_B(Brs, cur);
        SG_BR(nxt, t + 1);
        BAR(); MFMA16(accR);
        asm volatile("s_waitcnt vmcnt(4)" ::: "memory");
        BAR();
    }
    {
        const int cur = 8192;
        bf16x8 aR[4][2], bR[2][2];
        RD_AALL(cur); RD_B(Bks, cur);
        BAR(); MFMA16(accK);
        asm volatile("s_waitcnt vmcnt(2)" ::: "memory");
        BAR();
        RD_B(Bvs, cur);
        BAR(); MFMA16(accV);
        asm volatile("s_waitcnt vmcnt(0)" ::: "memory");
        BAR();
        RD_B(Brs, cur);
        MFMA16(accR);
    }
#undef SG_A
#undef SG_BK
#undef SG_BV
#undef SG_BR
#undef RD_AALL
#undef RD_B
#undef MFMA16

    const int orow0 = brow + wrow * 64;
    const int ocol0 = bcol + wcol * 32;
    const int rbase = q * 4;
    const int b = brow >> 12;
    float dcol[2][4];
#pragma unroll
    for (int ni = 0; ni < 2; ++ni)
#pragma unroll
        for (int d = 0; d < 4; ++d)
            dcol[ni][d] = dec[b * (D_ * H_) + d * H_ + (ocol0 + ni * 16 + l15)];
#pragma unroll
    for (int mi = 0; mi < 4; ++mi)
#pragma unroll
        for (int j = 0; j < 4; ++j) {
            const int r = orow0 + mi * 16 + rbase + j;
            const f32x4 lw = *(const f32x4*)(lgw + (size_t)r * 4);
            const float wsum = lw[0] + lw[1] + lw[2] + lw[3];
#pragma unroll
            for (int ni = 0; ni < 2; ++ni) {
                const size_t idx = (size_t)r * 1024 + (ocol0 + ni * 16 + l15);
                const float kvf = b2f(f2b(accV[mi][ni][j] * b2f(f2b(accK[mi][ni][j]))));
                const float rv  = 1.0f / (1.0f + __expf(-accR[mi][ni][j]));
                const float w   = lw[0] * dcol[ni][0] + lw[1] * dcol[ni][1]
                                + lw[2] * dcol[ni][2] + lw[3] * dcol[ni][3]
                                + wsum * kvf;
                Co[idx] = f2b(rv * w);
            }
        }
}

// ---------------------------------------------------------------------------
// o-GEMM, R12-profile mirror: out = f32(o @ Wo^T)
// 256x256 tile, 8 waves (4Mx2N, 64x128/wave), BK=64. LDS: A 2x32KB+B 2x32KB.
// 4 phases/tile x {4 ds_read + 16 MFMA}; aR (8 reads) once per tile in P1:
//   P1: rd aR + b(n01); stage Bh0(t+1); BAR; MFMA n01; BAR
//   P2: rd b(n23);      stage Bh1(t+1); BAR; MFMA n23; BAR
//   P3: rd b(n45);      stage A01(t+2)->curA (aR reads done P1); BAR; n45; BAR
//   P4: rd b(n67);      stage A23(t+2)->curA; BAR; n67; vmcnt(4); BAR
// FIFO: tile-end leaves A(t+2):4 in flight; never vmcnt(0) in main loop.
// Per-element K-order identical to R13 gemm_o -> absmax bit-identical.
// ---------------------------------------------------------------------------
__global__ __launch_bounds__(512, 2) void gemm_o3(
    const unsigned short* __restrict__ A,
    const unsigned short* __restrict__ Wt,
    float* __restrict__ outf)
{
    __shared__ __align__(16) unsigned short As[2 * 16384];   // [2][256][64]
    __shared__ __align__(16) unsigned short Bs[2 * 16384];

    const int tid  = threadIdx.x;
    const int wid  = tid >> 6;        // 0..7
    const int lane = tid & 63;
    const int l15  = lane & 15;
    const int q    = lane >> 4;
    const int wrow = wid >> 1;        // 0..3 (64-row quarter)
    const int wcol = wid & 1;         // 0..1 (128-col half)
    const int brow = blockIdx.x * 256;
    const int bcol = blockIdx.y * 256;

    // staging: 4 slots each for A and B; slot i covers rows [64i, 64i+64)
    int offA[4], offB[4], dstq[4];
#pragma unroll
    for (int i = 0; i < 4; ++i) {
        const int G   = i * 512 + tid;
        const int row = G >> 3;
        const int cg  = (G & 7) ^ (row & 7);
        offA[i] = (brow + row) * 1024 + cg * 8;
        offB[i] = (bcol + row) * 1024 + cg * 8;
        dstq[i] = G * 8;
    }

    int gx[2];
#pragma unroll
    for (int ks = 0; ks < 2; ++ks) gx[ks] = ((ks * 4 + q) ^ (l15 & 7)) * 8;
    int aB[4], bB[8];
#pragma unroll
    for (int mi = 0; mi < 4; ++mi) aB[mi] = (wrow * 64 + mi * 16 + l15) * 64;
#pragma unroll
    for (int ni = 0; ni < 8; ++ni) bB[ni] = (wcol * 128 + ni * 16 + l15) * 64;

    f32x4 acc[4][8];
#pragma unroll
    for (int i = 0; i < 4; ++i)
#pragma unroll
        for (int j = 0; j < 8; ++j)
            acc[i][j] = (f32x4){0.f, 0.f, 0.f, 0.f};

#define SG_A01(bo, tau) do { GLLDS(A + offA[0] + (tau) * 64, As + (bo) + dstq[0]); \
                             GLLDS(A + offA[1] + (tau) * 64, As + (bo) + dstq[1]); } while (0)
#define SG_A23(bo, tau) do { GLLDS(A + offA[2] + (tau) * 64, As + (bo) + dstq[2]); \
                             GLLDS(A + offA[3] + (tau) * 64, As + (bo) + dstq[3]); } while (0)
#define SG_BH0(bo, tau) do { GLLDS(Wt + offB[0] + (tau) * 64, Bs + (bo) + dstq[0]); \
                             GLLDS(Wt + offB[1] + (tau) * 64, Bs + (bo) + dstq[1]); } while (0)
#define SG_BH1(bo, tau) do { GLLDS(Wt + offB[2] + (tau) * 64, Bs + (bo) + dstq[2]); \
                             GLLDS(Wt + offB[3] + (tau) * 64, Bs + (bo) + dstq[3]); } while (0)
#define RD_AALL(CUR)                                                          \
    _Pragma("unroll") for (int mi = 0; mi < 4; ++mi)                          \
    _Pragma("unroll") for (int ks = 0; ks < 2; ++ks)                          \
        aR[mi][ks] = *(const bf16x8*)&As[(CUR) + aB[mi] + gx[ks]];
#define RD_B2(CUR, N0)                                                        \
    _Pragma("unroll") for (int nj = 0; nj < 2; ++nj)                          \
    _Pragma("unroll") for (int ks = 0; ks < 2; ++ks)                          \
        bR[nj][ks] = *(const bf16x8*)&Bs[(CUR) + bB[(N0) + nj] + gx[ks]];
#define MFMA16(N0)                                                            \
    __builtin_amdgcn_s_setprio(1);                                            \
    _Pragma("unroll") for (int mi = 0; mi < 4; ++mi)                          \
    _Pragma("unroll") for (int nj = 0; nj < 2; ++nj)                          \
    _Pragma("unroll") for (int ks = 0; ks < 2; ++ks)                          \
        acc[mi][(N0) + nj] = __builtin_amdgcn_mfma_f32_16x16x32_bf16(         \
            aR[mi][ks], bR[nj][ks], acc[mi][(N0) + nj], 0, 0, 0);             \
    __builtin_amdgcn_s_setprio(0);

    // prologue: A(0) 4, B(0) 4, A(1) 4; drain first 8, leave A(1) in flight
    SG_A01(0, 0); SG_A23(0, 0);
    SG_BH0(0, 0); SG_BH1(0, 0);
    SG_A01(16384, 1); SG_A23(16384, 1);
    asm volatile("s_waitcnt vmcnt(4)" ::: "memory");
    BAR();

#pragma unroll 1
    for (int t = 0; t < 15; ++t) {
        const int cur = (t & 1) << 14;        // 0 / 16384
        const int nxt = cur ^ 16384;
        bf16x8 aR[4][2], bR[2][2];

        // P1: aR(once/tile) + b(n01); stage Bh0(t+1)
        RD_AALL(cur); RD_B2(cur, 0);
        SG_BH0(nxt, t + 1);
        BAR(); MFMA16(0); BAR();

        // P2: b(n23); stage Bh1(t+1)
        RD_B2(cur, 2);
        SG_BH1(nxt, t + 1);
        BAR(); MFMA16(2); BAR();

        // P3: b(n45); stage A01(t+2) into curA (aR reads done at P1 bar)
        RD_B2(cur, 4);
        if (t < 14) SG_A01(cur, t + 2);
        BAR(); MFMA16(4); BAR();

        // P4: b(n67); stage A23(t+2); counted tile-end drain
        RD_B2(cur, 6);
        if (t < 14) SG_A23(cur, t + 2);
        BAR(); MFMA16(6);
        if (t < 14) asm volatile("s_waitcnt vmcnt(4)" ::: "memory");
        else        asm volatile("s_waitcnt vmcnt(0)" ::: "memory");
        BAR();
    }
    // tail: tile 15 fully resident, no stages -> no barriers
    {
        const int cur = 16384;
        bf16x8 aR[4][2], bR[2][2];
        RD_AALL(cur);
        RD_B2(cur, 0); MFMA16(0);
        RD_B2(cur, 2); MFMA16(2);
        RD_B2(cur, 4); MFMA16(4);
        RD_B2(cur, 6); MFMA16(6);
    }
#undef SG_A01
#undef SG_A23
#undef SG_BH0
#undef SG_BH1
#undef RD_AALL
#undef RD_B2
#undef MFMA16

    const int orow0 = brow + wrow * 64;
    const int ocol0 = bcol + wcol * 128;
    const int rbase = q * 4;
#pragma unroll
    for (int mi = 0; mi < 4; ++mi)
#pragma unroll
        for (int j = 0; j < 4; ++j) {
            const size_t r = (size_t)(orow0 + mi * 16 + rbase + j);
#pragma unroll
            for (int ni = 0; ni < 8; ++ni)
                outf[r * 1024 + (ocol0 + ni * 16 + l15)] = acc[mi][ni][j];
        }
}

// ---------------------------------------------------------------------------
extern "C" void kernel_launch(void* const* d_in, const int* in_sizes, int n_in,
                              void* d_out, int out_size, void* d_ws, size_t ws_size,
                              hipStream_t stream)
{
    const float* x   = (const float*)d_in[0];
    const float* st  = (const float*)d_in[1];
    const float* tdm = (const float*)d_in[2];
    const float* Wl  = (const float*)d_in[3];
    const float* bl  = (const float*)d_in[4];
    const float* Wv  = (const float*)d_in[5];
    const float* Wk  = (const float*)d_in[6];
    const float* Wr  = (const float*)d_in[7];
    const float* Wo  = (const float*)d_in[8];
    float* out = (float*)d_out;                    // f32 output

    char* ws = (char*)d_ws;
    unsigned short* buf  = (unsigned short*)(ws + WS_BUF);   // o
    unsigned short* wk_b = (unsigned short*)(ws + WS_WK);    // [4][H][H]: k,v,r,o
    unsigned short* wv_b = wk_b + 1 * (H_ * H_);
    unsigned short* wr_b = wk_b + 2 * (H_ * H_);
    unsigned short* wo_b = wk_b + 3 * (H_ * H_);
    float* lgw = (float*)(ws + WS_LGW);
    float* dec = (float*)(ws + WS_DEC);

    // bf16 x scratch inside d_out's f32 output-0 region; final GEMM
    // fully overwrites it afterwards.
    unsigned short* xb = (unsigned short*)out;

    // small kernels
    decstate_k<<<(B_ * D_ * H_ + 255) / 256, 256, 0, stream>>>(st, tdm, dec);
    logcvt_k<<<M_ / 4, 256, 0, stream>>>(x, Wl, bl, lgw, xb);
    newstate_k<<<(B_ * H_) / 4, 256, 0, stream>>>(x, Wk, Wv, dec, out + OUT_MAIN);
    cvtw_k<<<dim3(1024, 4), 256, 0, stream>>>(Wk, Wv, Wr, Wo, wk_b);

    // buf = o = sigmoid(x@Wr^T) * (lw.dec + wsum*(x@Wk^T * x@Wv^T))
    gemm_kvr<<<dim3(8, 128), 512, 0, stream>>>(
        xb, wk_b, wv_b, wr_b, buf, lgw, dec);

    // out = f32(o @ Wo^T)  [R12-profile mirror]
    gemm_o3<<<dim3(M_ / 256, H_ / 256), 512, 0, stream>>>(buf, wo_b, out);
}

// Round 18
// 172.172 us; speedup vs baseline: 1.1023x; 1.0569x over previous
//
#include <hip/hip_runtime.h>

// HierarchicalTimeAttention  B=4, T=4096, H=1024, D=4
// R18: consolidation at best-known state. gemm_o reverted to R8 structure
// (51us; R14's 2ph=65, R17's 4ph-mirror=57 both regressed -> fusion's
// multi-acc-per-staged-byte was the R12/R13 win, not the schedule).
// decstate_k folded into newstate_k (-1 dispatch). kvr = R15 verbatim
// (112.5us, 38% MfmaUtil, XCD swizzle).
// R15 best: 175.4us = kvr 112.5 + gemm_o 51 + small 12.
#define B_ 4
#define T_ 4096
#define H_ 1024
#define D_ 4
#define M_ (B_ * T_)          // 16384
#define OUT_MAIN (M_ * H_)    // 16,777,216 (f32 elements)

#define WS_BUF  0UL           // bf16 [M][H]: o   (32MB)
#define WS_WK   33554432UL    // bf16 Wk,Wv,Wr,Wo contiguous [4][H][H] (8MB)
#define WS_LGW  41943040UL    // f32 softmax weights [M][4] (256KB)
#define WS_DEC  42205184UL    // f32 decayed_state0 [B][D][H] (64KB)

typedef __bf16 bf16x8 __attribute__((ext_vector_type(8)));
typedef unsigned short u16x4 __attribute__((ext_vector_type(4)));
typedef float f32x4 __attribute__((ext_vector_type(4)));

__device__ __forceinline__ float b2f(unsigned short u) {
    union { unsigned int i; float f; } c;
    c.i = ((unsigned int)u) << 16;
    return c.f;
}
__device__ __forceinline__ unsigned short f2b(float f) {
    union { float f; unsigned int i; } c;
    c.f = f;
    unsigned int x = c.i;
    unsigned int r = (x + 0x7FFFu + ((x >> 16) & 1u)) >> 16;  // RNE
    return (unsigned short)r;
}

#define BAR()  asm volatile("s_barrier" ::: "memory")
#define GLLDS(gsrc, ldst)                                                     \
    __builtin_amdgcn_global_load_lds(                                         \
        (const __attribute__((address_space(1))) unsigned int*)(gsrc),        \
        (__attribute__((address_space(3))) unsigned int*)(ldst), 16, 0, 0)

// ---------------------------------------------------------------------------
__global__ __launch_bounds__(256) void cvtw_k(
    const float* __restrict__ s0, const float* __restrict__ s1,
    const float* __restrict__ s2, const float* __restrict__ s3,
    unsigned short* __restrict__ d)
{
    const int w = blockIdx.y;
    const float* s = (w == 0) ? s0 : (w == 1) ? s1 : (w == 2) ? s2 : s3;
    const int i = blockIdx.x * 256 + threadIdx.x;
    const f32x4 v = ((const f32x4*)s)[i];
    u16x4 o;
    o[0] = f2b(v[0]); o[1] = f2b(v[1]); o[2] = f2b(v[2]); o[3] = f2b(v[3]);
    ((u16x4*)(d + (size_t)w * (H_ * H_)))[i] = o;
}

// ---------------------------------------------------------------------------
__global__ __launch_bounds__(256) void logcvt_k(
    const float* __restrict__ X, const float* __restrict__ Wl,
    const float* __restrict__ bl, float* __restrict__ lgw,
    unsigned short* __restrict__ xb)
{
    const int wid  = threadIdx.x >> 6;
    const int lane = threadIdx.x & 63;
    const int row  = blockIdx.x * 4 + wid;
    const float* xp = X + (size_t)row * H_;
    unsigned short* xo = xb + (size_t)row * H_;

    float acc[D_] = {0.f, 0.f, 0.f, 0.f};
    for (int h = lane * 4; h < H_; h += 256) {
        const f32x4 xv = *(const f32x4*)(xp + h);
        u16x4 xc;
        xc[0] = f2b(xv[0]); xc[1] = f2b(xv[1]);
        xc[2] = f2b(xv[2]); xc[3] = f2b(xv[3]);
        *(u16x4*)(xo + h) = xc;
#pragma unroll
        for (int d = 0; d < D_; ++d) {
            const f32x4 wv = *(const f32x4*)(Wl + d * H_ + h);
            acc[d] += xv[0] * wv[0] + xv[1] * wv[1] + xv[2] * wv[2] + xv[3] * wv[3];
        }
    }
#pragma unroll
    for (int off = 32; off; off >>= 1)
#pragma unroll
        for (int d = 0; d < D_; ++d) acc[d] += __shfl_xor(acc[d], off, 64);

    if (lane == 0) {
        float l[D_];
#pragma unroll
        for (int d = 0; d < D_; ++d) l[d] = acc[d] + bl[d];
        const float mx = fmaxf(fmaxf(l[0], l[1]), fmaxf(l[2], l[3]));
        float e[D_], s = 0.f;
#pragma unroll
        for (int d = 0; d < D_; ++d) { e[d] = __expf(l[d] - mx); s += e[d]; }
        const float inv = 1.0f / s;
        f32x4 o;
#pragma unroll
        for (int d = 0; d < D_; ++d) o[d] = e[d] * inv;
        *(f32x4*)(lgw + (size_t)row * 4) = o;
    }
}

// ---------------------------------------------------------------------------
// newstate_k (+ folded decstate): one wave per (b,h).
//   k_last = x[b,T-1,:].Wk[h,:], v_last = x[b,T-1,:].Wv[h,:]   (f32 exact)
//   dec[b,d,h] = st[b,d,h]*exp(-exp(tdm[d,h]));  out2 = dec + k_last*v_last
// ---------------------------------------------------------------------------
__global__ __launch_bounds__(256) void newstate_k(
    const float* __restrict__ X, const float* __restrict__ Wk,
    const float* __restrict__ Wv, const float* __restrict__ st,
    const float* __restrict__ tdm,
    float* __restrict__ dec, float* __restrict__ out2)
{
    const int wid  = threadIdx.x >> 6;
    const int lane = threadIdx.x & 63;
    const int row  = blockIdx.x * 4 + wid;   // 0..B*H-1
    const int b    = row >> 10;
    const int h    = row & (H_ - 1);
    const float* xp = X + ((size_t)(b * T_ + (T_ - 1))) * H_;

    float ak = 0.f, av = 0.f;
    for (int j = lane * 4; j < H_; j += 256) {
        const f32x4 xv = *(const f32x4*)(xp + j);
        const f32x4 wk = *(const f32x4*)(Wk + (size_t)h * H_ + j);
        const f32x4 wv = *(const f32x4*)(Wv + (size_t)h * H_ + j);
        ak += xv[0]*wk[0] + xv[1]*wk[1] + xv[2]*wk[2] + xv[3]*wk[3];
        av += xv[0]*wv[0] + xv[1]*wv[1] + xv[2]*wv[2] + xv[3]*wv[3];
    }
#pragma unroll
    for (int off = 32; off; off >>= 1) {
        ak += __shfl_xor(ak, off, 64);
        av += __shfl_xor(av, off, 64);
    }
    if (lane == 0) {
        const float kv = ak * av;
#pragma unroll
        for (int d = 0; d < D_; ++d) {
            const size_t i = (size_t)(b * D_ + d) * H_ + h;
            const float dv = st[i] * __expf(-__expf(tdm[d * H_ + h]));
            dec[i]  = dv;
            out2[i] = dv + kv;
        }
    }
}

// ---------------------------------------------------------------------------
// FUSED KVR GEMM + o-epilogue (R15 verbatim: 112.5us, 38% MfmaUtil).
// 128x128 tile, 8 waves 64x32, BK=64, 3 phases/tile, counted vmcnt(6/6/4),
// XCD swizzle (each XCD owns 16 contiguous brow-bands), R8 LDS swizzle.
// ---------------------------------------------------------------------------
__global__ __launch_bounds__(512, 2) void gemm_kvr(
    const unsigned short* __restrict__ A,
    const unsigned short* __restrict__ Wk,
    const unsigned short* __restrict__ Wv,
    const unsigned short* __restrict__ Wr,
    unsigned short* __restrict__ Co,
    const float* __restrict__ lgw,
    const float* __restrict__ dec)
{
    __shared__ __align__(16) unsigned short As [2 * 8192];   // [2][128][64]
    __shared__ __align__(16) unsigned short Bks[2 * 8192];
    __shared__ __align__(16) unsigned short Bvs[2 * 8192];
    __shared__ __align__(16) unsigned short Brs[2 * 8192];

    const int tid  = threadIdx.x;
    const int wid  = tid >> 6;
    const int lane = tid & 63;
    const int l15  = lane & 15;
    const int q    = lane >> 4;
    const int wrow = wid >> 2;        // 0..1
    const int wcol = wid & 3;         // 0..3

    const int lin  = blockIdx.y * 8 + blockIdx.x;
    const int xcd  = lin & 7;
    const int slot = lin >> 3;                // 0..127
    const int brow = (xcd * 16 + (slot >> 3)) * 128;
    const int bcol = (slot & 7) * 128;

    const int g0row = tid >> 3, g0cg = (tid & 7) ^ (g0row & 7);
    const int g1row = 64 + g0row, g1cg = (tid & 7) ^ (g1row & 7);
    const int offA0 = (brow + g0row) * 1024 + g0cg * 8;
    const int offA1 = (brow + g1row) * 1024 + g1cg * 8;
    const int offB0 = (bcol + g0row) * 1024 + g0cg * 8;
    const int offB1 = (bcol + g1row) * 1024 + g1cg * 8;
    const int dst0 = tid * 8;
    const int dst1 = 4096 + tid * 8;

    int gx[2];
#pragma unroll
    for (int ks = 0; ks < 2; ++ks) gx[ks] = ((ks * 4 + q) ^ (l15 & 7)) * 8;
    int aB[4], bB[2];
#pragma unroll
    for (int mi = 0; mi < 4; ++mi) aB[mi] = (wrow * 64 + mi * 16 + l15) * 64;
#pragma unroll
    for (int ni = 0; ni < 2; ++ni) bB[ni] = (wcol * 32 + ni * 16 + l15) * 64;

    f32x4 accK[4][2], accV[4][2], accR[4][2];
#pragma unroll
    for (int i = 0; i < 4; ++i)
#pragma unroll
        for (int j = 0; j < 2; ++j) {
            accK[i][j] = (f32x4){0.f, 0.f, 0.f, 0.f};
            accV[i][j] = (f32x4){0.f, 0.f, 0.f, 0.f};
            accR[i][j] = (f32x4){0.f, 0.f, 0.f, 0.f};
        }

#define SG_A(bo, tau)  do { GLLDS(A  + offA0 + (tau) * 64, As  + (bo) + dst0); \
                            GLLDS(A  + offA1 + (tau) * 64, As  + (bo) + dst1); } while (0)
#define SG_BK(bo, tau) do { GLLDS(Wk + offB0 + (tau) * 64, Bks + (bo) + dst0); \
                            GLLDS(Wk + offB1 + (tau) * 64, Bks + (bo) + dst1); } while (0)
#define SG_BV(bo, tau) do { GLLDS(Wv + offB0 + (tau) * 64, Bvs + (bo) + dst0); \
                            GLLDS(Wv + offB1 + (tau) * 64, Bvs + (bo) + dst1); } while (0)
#define SG_BR(bo, tau) do { GLLDS(Wr + offB0 + (tau) * 64, Brs + (bo) + dst0); \
                            GLLDS(Wr + offB1 + (tau) * 64, Brs + (bo) + dst1); } while (0)
#define RD_AALL(CUR)                                                          \
    _Pragma("unroll") for (int mi = 0; mi < 4; ++mi)                          \
    _Pragma("unroll") for (int ks = 0; ks < 2; ++ks)                          \
        aR[mi][ks] = *(const bf16x8*)&As[(CUR) + aB[mi] + gx[ks]];
#define RD_B(ARR, CUR)                                                        \
    _Pragma("unroll") for (int nj = 0; nj < 2; ++nj)                          \
    _Pragma("unroll") for (int ks = 0; ks < 2; ++ks)                          \
        bR[nj][ks] = *(const bf16x8*)&ARR[(CUR) + bB[nj] + gx[ks]];
#define MFMA16(ACC)                                                           \
    __builtin_amdgcn_s_setprio(1);                                            \
    _Pragma("unroll") for (int mi = 0; mi < 4; ++mi)                          \
    _Pragma("unroll") for (int nj = 0; nj < 2; ++nj)                          \
    _Pragma("unroll") for (int ks = 0; ks < 2; ++ks)                          \
        ACC[mi][nj] = __builtin_amdgcn_mfma_f32_16x16x32_bf16(                \
            aR[mi][ks], bR[nj][ks], ACC[mi][nj], 0, 0, 0);                    \
    __builtin_amdgcn_s_setprio(0);

    SG_A(0, 0); SG_BK(0, 0); SG_BV(0, 0); SG_BR(0, 0);
    asm volatile("s_waitcnt vmcnt(4)" ::: "memory");
    BAR();

#pragma unroll 1
    for (int t = 0; t < 15; ++t) {
        const int cur = (t & 1) << 13;
        const int nxt = cur ^ 8192;
        bf16x8 aR[4][2], bR[2][2];

        RD_AALL(cur); RD_B(Bks, cur);
        SG_A(nxt, t + 1); SG_BK(nxt, t + 1);
        BAR(); MFMA16(accK);
        asm volatile("s_waitcnt vmcnt(6)" ::: "memory");
        BAR();

        RD_B(Bvs, cur);
        SG_BV(nxt, t + 1);
        BAR(); MFMA16(accV);
        asm volatile("s_waitcnt vmcnt(6)" ::: "memory");
        BAR();

        RD_B(Brs, cur);
        SG_BR(nxt, t + 1);
        BAR(); MFMA16(accR);
        asm volatile("s_waitcnt vmcnt(4)" ::: "memory");
        BAR();
    }
    {
        const int cur = 8192;
        bf16x8 aR[4][2], bR[2][2];
        RD_AALL(cur); RD_B(Bks, cur);
        BAR(); MFMA16(accK);
        asm volatile("s_waitcnt vmcnt(2)" ::: "memory");
        BAR();
        RD_B(Bvs, cur);
        BAR(); MFMA16(accV);
        asm volatile("s_waitcnt vmcnt(0)" ::: "memory");
        BAR();
        RD_B(Brs, cur);
        MFMA16(accR);
    }
#undef SG_A
#undef SG_BK
#undef SG_BV
#undef SG_BR
#undef RD_AALL
#undef RD_B
#undef MFMA16

    const int orow0 = brow + wrow * 64;
    const int ocol0 = bcol + wcol * 32;
    const int rbase = q * 4;
    const int b = brow >> 12;
    float dcol[2][4];
#pragma unroll
    for (int ni = 0; ni < 2; ++ni)
#pragma unroll
        for (int d = 0; d < 4; ++d)
            dcol[ni][d] = dec[b * (D_ * H_) + d * H_ + (ocol0 + ni * 16 + l15)];
#pragma unroll
    for (int mi = 0; mi < 4; ++mi)
#pragma unroll
        for (int j = 0; j < 4; ++j) {
            const int r = orow0 + mi * 16 + rbase + j;
            const f32x4 lw = *(const f32x4*)(lgw + (size_t)r * 4);
            const float wsum = lw[0] + lw[1] + lw[2] + lw[3];
#pragma unroll
            for (int ni = 0; ni < 2; ++ni) {
                const size_t idx = (size_t)r * 1024 + (ocol0 + ni * 16 + l15);
                const float kvf = b2f(f2b(accV[mi][ni][j] * b2f(f2b(accK[mi][ni][j]))));
                const float rv  = 1.0f / (1.0f + __expf(-accR[mi][ni][j]));
                const float w   = lw[0] * dcol[ni][0] + lw[1] * dcol[ni][1]
                                + lw[2] * dcol[ni][2] + lw[3] * dcol[ni][3]
                                + wsum * kvf;
                Co[idx] = f2b(rv * w);
            }
        }
}

// ---------------------------------------------------------------------------
// o-GEMM (R8 structure verbatim, 51us — best of 3 tested structures):
// out = f32(o @ Wo^T). 256x256, 8 waves, BK=64, 4 phases, dbuf, swizzle.
// ---------------------------------------------------------------------------
__global__ __launch_bounds__(512, 2) void gemm_o(
    const unsigned short* __restrict__ A,
    const unsigned short* __restrict__ Wt,
    float* __restrict__ outf)
{
    __shared__ __align__(16) unsigned short As[2 * 256 * 64];
    __shared__ __align__(16) unsigned short Bs[2 * 256 * 64];

    const int tid  = threadIdx.x;
    const int wid  = tid >> 6;
    const int lane = tid & 63;
    const int l15  = lane & 15;
    const int l7   = lane & 7;
    const int wrow = wid >> 2;
    const int wcol = wid & 3;
    const int brow = blockIdx.x * 256;
    const int bcol = blockIdx.y * 256;

    int offA[4], offB[4], dst[4];
#pragma unroll
    for (int i = 0; i < 4; ++i) {
        const int G   = i * 512 + tid;
        const int row = G >> 3;
        const int cg  = (G & 7) ^ (row & 7);
        offA[i] = (brow + row) * 1024 + cg * 8;
        offB[i] = (bcol + row) * 1024 + cg * 8;
        dst[i]  = G * 8;
    }

    int aB[8], bB[4], gx[2];
#pragma unroll
    for (int ks = 0; ks < 2; ++ks) gx[ks] = ((ks * 4 + (lane >> 4)) ^ l7) * 8;
#pragma unroll
    for (int mi = 0; mi < 8; ++mi) aB[mi] = (wrow * 128 + mi * 16 + l15) * 64;
#pragma unroll
    for (int ni = 0; ni < 4; ++ni) bB[ni] = (wcol * 64 + ni * 16 + l15) * 64;

    f32x4 acc[8][4];
#pragma unroll
    for (int i = 0; i < 8; ++i)
#pragma unroll
        for (int j = 0; j < 4; ++j)
            acc[i][j] = (f32x4){0.f, 0.f, 0.f, 0.f};

#pragma unroll
    for (int i = 0; i < 4; ++i) {
        GLLDS(A  + offA[i], As + dst[i]);
        GLLDS(Wt + offB[i], Bs + dst[i]);
    }
    asm volatile("s_waitcnt vmcnt(0)" ::: "memory");
    BAR();

#pragma unroll 1
    for (int t = 0; t < 16; ++t) {
        const int cur = (t & 1) * 16384;
        const int nxt = 16384 - cur;
        const int kk  = (t + 1) * 64;
        const bool st = (t < 15);
        bf16x8 aR[4][2], bR[4][2];

#pragma unroll
        for (int mi = 0; mi < 4; ++mi)
#pragma unroll
            for (int ks = 0; ks < 2; ++ks)
                aR[mi][ks] = *(const bf16x8*)&As[cur + aB[mi] + gx[ks]];
#pragma unroll
        for (int ni = 0; ni < 2; ++ni)
#pragma unroll
            for (int ks = 0; ks < 2; ++ks)
                bR[ni][ks] = *(const bf16x8*)&Bs[cur + bB[ni] + gx[ks]];
        if (st) {
            GLLDS(A  + offA[0] + kk, As + nxt + dst[0]);
            GLLDS(A  + offA[1] + kk, As + nxt + dst[1]);
            GLLDS(Wt + offB[0] + kk, Bs + nxt + dst[0]);
        }
        BAR();
        __builtin_amdgcn_s_setprio(1);
#pragma unroll
        for (int mi = 0; mi < 4; ++mi)
#pragma unroll
            for (int ni = 0; ni < 2; ++ni)
#pragma unroll
                for (int ks = 0; ks < 2; ++ks)
                    acc[mi][ni] = __builtin_amdgcn_mfma_f32_16x16x32_bf16(
                        aR[mi][ks], bR[ni][ks], acc[mi][ni], 0, 0, 0);
        __builtin_amdgcn_s_setprio(0);
        BAR();

#pragma unroll
        for (int ni = 2; ni < 4; ++ni)
#pragma unroll
            for (int ks = 0; ks < 2; ++ks)
                bR[ni][ks] = *(const bf16x8*)&Bs[cur + bB[ni] + gx[ks]];
        if (st) {
            GLLDS(A  + offA[2] + kk, As + nxt + dst[2]);
            GLLDS(A  + offA[3] + kk, As + nxt + dst[3]);
            GLLDS(Wt + offB[1] + kk, Bs + nxt + dst[1]);
        }
        BAR();
        __builtin_amdgcn_s_setprio(1);
#pragma unroll
        for (int mi = 0; mi < 4; ++mi)
#pragma unroll
            for (int ni = 2; ni < 4; ++ni)
#pragma unroll
                for (int ks = 0; ks < 2; ++ks)
                    acc[mi][ni] = __builtin_amdgcn_mfma_f32_16x16x32_bf16(
                        aR[mi][ks], bR[ni][ks], acc[mi][ni], 0, 0, 0);
        __builtin_amdgcn_s_setprio(0);
        BAR();

#pragma unroll
        for (int mi = 0; mi < 4; ++mi)
#pragma unroll
            for (int ks = 0; ks < 2; ++ks)
                aR[mi][ks] = *(const bf16x8*)&As[cur + aB[4 + mi] + gx[ks]];
        if (st) {
            GLLDS(Wt + offB[2] + kk, Bs + nxt + dst[2]);
            GLLDS(Wt + offB[3] + kk, Bs + nxt + dst[3]);
        }
        BAR();
        __builtin_amdgcn_s_setprio(1);
#pragma unroll
        for (int mi = 0; mi < 4; ++mi)
#pragma unroll
            for (int ni = 2; ni < 4; ++ni)
#pragma unroll
                for (int ks = 0; ks < 2; ++ks)
                    acc[4 + mi][ni] = __builtin_amdgcn_mfma_f32_16x16x32_bf16(
                        aR[mi][ks], bR[ni][ks], acc[4 + mi][ni], 0, 0, 0);
        __builtin_amdgcn_s_setprio(0);
        BAR();

        __builtin_amdgcn_s_setprio(1);
#pragma unroll
        for (int mi = 0; mi < 4; ++mi)
#pragma unroll
            for (int ni = 0; ni < 2; ++ni)
#pragma unroll
                for (int ks = 0; ks < 2; ++ks)
                    acc[4 + mi][ni] = __builtin_amdgcn_mfma_f32_16x16x32_bf16(
                        aR[mi][ks], bR[ni][ks], acc[4 + mi][ni], 0, 0, 0);
        __builtin_amdgcn_s_setprio(0);
        asm volatile("s_waitcnt vmcnt(0)" ::: "memory");
        BAR();
    }

    const int orow0 = brow + wrow * 128;
    const int ocol0 = bcol + wcol * 64;
    const int rbase = (lane >> 4) * 4;
#pragma unroll
    for (int mi = 0; mi < 8; ++mi)
#pragma unroll
        for (int j = 0; j < 4; ++j) {
            const size_t r = (size_t)(orow0 + mi * 16 + rbase + j);
#pragma unroll
            for (int ni = 0; ni < 4; ++ni)
                outf[r * 1024 + (ocol0 + ni * 16 + l15)] = acc[mi][ni][j];
        }
}

// ---------------------------------------------------------------------------
extern "C" void kernel_launch(void* const* d_in, const int* in_sizes, int n_in,
                              void* d_out, int out_size, void* d_ws, size_t ws_size,
                              hipStream_t stream)
{
    const float* x   = (const float*)d_in[0];
    const float* st  = (const float*)d_in[1];
    const float* tdm = (const float*)d_in[2];
    const float* Wl  = (const float*)d_in[3];
    const float* bl  = (const float*)d_in[4];
    const float* Wv  = (const float*)d_in[5];
    const float* Wk  = (const float*)d_in[6];
    const float* Wr  = (const float*)d_in[7];
    const float* Wo  = (const float*)d_in[8];
    float* out = (float*)d_out;                    // f32 output

    char* ws = (char*)d_ws;
    unsigned short* buf  = (unsigned short*)(ws + WS_BUF);   // o
    unsigned short* wk_b = (unsigned short*)(ws + WS_WK);    // [4][H][H]: k,v,r,o
    unsigned short* wv_b = wk_b + 1 * (H_ * H_);
    unsigned short* wr_b = wk_b + 2 * (H_ * H_);
    unsigned short* wo_b = wk_b + 3 * (H_ * H_);
    float* lgw = (float*)(ws + WS_LGW);
    float* dec = (float*)(ws + WS_DEC);

    // bf16 x scratch inside d_out's f32 output-0 region; final GEMM
    // fully overwrites it afterwards.
    unsigned short* xb = (unsigned short*)out;

    // small kernels (3 dispatches: logcvt, newstate(+dec), cvtw)
    logcvt_k<<<M_ / 4, 256, 0, stream>>>(x, Wl, bl, lgw, xb);
    newstate_k<<<(B_ * H_) / 4, 256, 0, stream>>>(x, Wk, Wv, st, tdm, dec, out + OUT_MAIN);
    cvtw_k<<<dim3(1024, 4), 256, 0, stream>>>(Wk, Wv, Wr, Wo, wk_b);

    // buf = o = sigmoid(x@Wr^T) * (lw.dec + wsum*(x@Wk^T * x@Wv^T))
    gemm_kvr<<<dim3(8, 128), 512, 0, stream>>>(
        xb, wk_b, wv_b, wr_b, buf, lgw, dec);

    // out = f32(o @ Wo^T)
    gemm_o<<<dim3(M_ / 256, H_ / 256), 512, 0, stream>>>(buf, wo_b, out);
}

// Round 19
// 171.051 us; speedup vs baseline: 1.1095x; 1.0066x over previous
//
#include <hip/hip_runtime.h>

// HierarchicalTimeAttention  B=4, T=4096, H=1024, D=4
// R19: gemm_o = R8 structure with ONLY stage placement changed (single var):
// B-halves staged P1/P2, A-halves P3/P4, FIFO {B0,B1,B2,B3,A0,A2,A1,A3};
// tile-end vmcnt(2) (next-P1 needs pos 1-6), P2-end vmcnt(4) (A1,A3 for P3).
// No drain-0 in main loop; every awaited load >=1.5 phases old.
// kvr + small kernels = R18 verbatim. R18 best: 172.2us.
#define B_ 4
#define T_ 4096
#define H_ 1024
#define D_ 4
#define M_ (B_ * T_)          // 16384
#define OUT_MAIN (M_ * H_)    // 16,777,216 (f32 elements)

#define WS_BUF  0UL           // bf16 [M][H]: o   (32MB)
#define WS_WK   33554432UL    // bf16 Wk,Wv,Wr,Wo contiguous [4][H][H] (8MB)
#define WS_LGW  41943040UL    // f32 softmax weights [M][4] (256KB)
#define WS_DEC  42205184UL    // f32 decayed_state0 [B][D][H] (64KB)

typedef __bf16 bf16x8 __attribute__((ext_vector_type(8)));
typedef unsigned short u16x4 __attribute__((ext_vector_type(4)));
typedef float f32x4 __attribute__((ext_vector_type(4)));

__device__ __forceinline__ float b2f(unsigned short u) {
    union { unsigned int i; float f; } c;
    c.i = ((unsigned int)u) << 16;
    return c.f;
}
__device__ __forceinline__ unsigned short f2b(float f) {
    union { float f; unsigned int i; } c;
    c.f = f;
    unsigned int x = c.i;
    unsigned int r = (x + 0x7FFFu + ((x >> 16) & 1u)) >> 16;  // RNE
    return (unsigned short)r;
}

#define BAR()  asm volatile("s_barrier" ::: "memory")
#define GLLDS(gsrc, ldst)                                                     \
    __builtin_amdgcn_global_load_lds(                                         \
        (const __attribute__((address_space(1))) unsigned int*)(gsrc),        \
        (__attribute__((address_space(3))) unsigned int*)(ldst), 16, 0, 0)

// ---------------------------------------------------------------------------
__global__ __launch_bounds__(256) void cvtw_k(
    const float* __restrict__ s0, const float* __restrict__ s1,
    const float* __restrict__ s2, const float* __restrict__ s3,
    unsigned short* __restrict__ d)
{
    const int w = blockIdx.y;
    const float* s = (w == 0) ? s0 : (w == 1) ? s1 : (w == 2) ? s2 : s3;
    const int i = blockIdx.x * 256 + threadIdx.x;
    const f32x4 v = ((const f32x4*)s)[i];
    u16x4 o;
    o[0] = f2b(v[0]); o[1] = f2b(v[1]); o[2] = f2b(v[2]); o[3] = f2b(v[3]);
    ((u16x4*)(d + (size_t)w * (H_ * H_)))[i] = o;
}

// ---------------------------------------------------------------------------
__global__ __launch_bounds__(256) void logcvt_k(
    const float* __restrict__ X, const float* __restrict__ Wl,
    const float* __restrict__ bl, float* __restrict__ lgw,
    unsigned short* __restrict__ xb)
{
    const int wid  = threadIdx.x >> 6;
    const int lane = threadIdx.x & 63;
    const int row  = blockIdx.x * 4 + wid;
    const float* xp = X + (size_t)row * H_;
    unsigned short* xo = xb + (size_t)row * H_;

    float acc[D_] = {0.f, 0.f, 0.f, 0.f};
    for (int h = lane * 4; h < H_; h += 256) {
        const f32x4 xv = *(const f32x4*)(xp + h);
        u16x4 xc;
        xc[0] = f2b(xv[0]); xc[1] = f2b(xv[1]);
        xc[2] = f2b(xv[2]); xc[3] = f2b(xv[3]);
        *(u16x4*)(xo + h) = xc;
#pragma unroll
        for (int d = 0; d < D_; ++d) {
            const f32x4 wv = *(const f32x4*)(Wl + d * H_ + h);
            acc[d] += xv[0] * wv[0] + xv[1] * wv[1] + xv[2] * wv[2] + xv[3] * wv[3];
        }
    }
#pragma unroll
    for (int off = 32; off; off >>= 1)
#pragma unroll
        for (int d = 0; d < D_; ++d) acc[d] += __shfl_xor(acc[d], off, 64);

    if (lane == 0) {
        float l[D_];
#pragma unroll
        for (int d = 0; d < D_; ++d) l[d] = acc[d] + bl[d];
        const float mx = fmaxf(fmaxf(l[0], l[1]), fmaxf(l[2], l[3]));
        float e[D_], s = 0.f;
#pragma unroll
        for (int d = 0; d < D_; ++d) { e[d] = __expf(l[d] - mx); s += e[d]; }
        const float inv = 1.0f / s;
        f32x4 o;
#pragma unroll
        for (int d = 0; d < D_; ++d) o[d] = e[d] * inv;
        *(f32x4*)(lgw + (size_t)row * 4) = o;
    }
}

// ---------------------------------------------------------------------------
// newstate_k (+ folded decstate): one wave per (b,h).
// ---------------------------------------------------------------------------
__global__ __launch_bounds__(256) void newstate_k(
    const float* __restrict__ X, const float* __restrict__ Wk,
    const float* __restrict__ Wv, const float* __restrict__ st,
    const float* __restrict__ tdm,
    float* __restrict__ dec, float* __restrict__ out2)
{
    const int wid  = threadIdx.x >> 6;
    const int lane = threadIdx.x & 63;
    const int row  = blockIdx.x * 4 + wid;   // 0..B*H-1
    const int b    = row >> 10;
    const int h    = row & (H_ - 1);
    const float* xp = X + ((size_t)(b * T_ + (T_ - 1))) * H_;

    float ak = 0.f, av = 0.f;
    for (int j = lane * 4; j < H_; j += 256) {
        const f32x4 xv = *(const f32x4*)(xp + j);
        const f32x4 wk = *(const f32x4*)(Wk + (size_t)h * H_ + j);
        const f32x4 wv = *(const f32x4*)(Wv + (size_t)h * H_ + j);
        ak += xv[0]*wk[0] + xv[1]*wk[1] + xv[2]*wk[2] + xv[3]*wk[3];
        av += xv[0]*wv[0] + xv[1]*wv[1] + xv[2]*wv[2] + xv[3]*wv[3];
    }
#pragma unroll
    for (int off = 32; off; off >>= 1) {
        ak += __shfl_xor(ak, off, 64);
        av += __shfl_xor(av, off, 64);
    }
    if (lane == 0) {
        const float kv = ak * av;
#pragma unroll
        for (int d = 0; d < D_; ++d) {
            const size_t i = (size_t)(b * D_ + d) * H_ + h;
            const float dv = st[i] * __expf(-__expf(tdm[d * H_ + h]));
            dec[i]  = dv;
            out2[i] = dv + kv;
        }
    }
}

// ---------------------------------------------------------------------------
// FUSED KVR GEMM + o-epilogue (R15/R18 verbatim: 112.5us, 38% MfmaUtil).
// ---------------------------------------------------------------------------
__global__ __launch_bounds__(512, 2) void gemm_kvr(
    const unsigned short* __restrict__ A,
    const unsigned short* __restrict__ Wk,
    const unsigned short* __restrict__ Wv,
    const unsigned short* __restrict__ Wr,
    unsigned short* __restrict__ Co,
    const float* __restrict__ lgw,
    const float* __restrict__ dec)
{
    __shared__ __align__(16) unsigned short As [2 * 8192];   // [2][128][64]
    __shared__ __align__(16) unsigned short Bks[2 * 8192];
    __shared__ __align__(16) unsigned short Bvs[2 * 8192];
    __shared__ __align__(16) unsigned short Brs[2 * 8192];

    const int tid  = threadIdx.x;
    const int wid  = tid >> 6;
    const int lane = tid & 63;
    const int l15  = lane & 15;
    const int q    = lane >> 4;
    const int wrow = wid >> 2;        // 0..1
    const int wcol = wid & 3;         // 0..3

    const int lin  = blockIdx.y * 8 + blockIdx.x;
    const int xcd  = lin & 7;
    const int slot = lin >> 3;                // 0..127
    const int brow = (xcd * 16 + (slot >> 3)) * 128;
    const int bcol = (slot & 7) * 128;

    const int g0row = tid >> 3, g0cg = (tid & 7) ^ (g0row & 7);
    const int g1row = 64 + g0row, g1cg = (tid & 7) ^ (g1row & 7);
    const int offA0 = (brow + g0row) * 1024 + g0cg * 8;
    const int offA1 = (brow + g1row) * 1024 + g1cg * 8;
    const int offB0 = (bcol + g0row) * 1024 + g0cg * 8;
    const int offB1 = (bcol + g1row) * 1024 + g1cg * 8;
    const int dst0 = tid * 8;
    const int dst1 = 4096 + tid * 8;

    int gx[2];
#pragma unroll
    for (int ks = 0; ks < 2; ++ks) gx[ks] = ((ks * 4 + q) ^ (l15 & 7)) * 8;
    int aB[4], bB[2];
#pragma unroll
    for (int mi = 0; mi < 4; ++mi) aB[mi] = (wrow * 64 + mi * 16 + l15) * 64;
#pragma unroll
    for (int ni = 0; ni < 2; ++ni) bB[ni] = (wcol * 32 + ni * 16 + l15) * 64;

    f32x4 accK[4][2], accV[4][2], accR[4][2];
#pragma unroll
    for (int i = 0; i < 4; ++i)
#pragma unroll
        for (int j = 0; j < 2; ++j) {
            accK[i][j] = (f32x4){0.f, 0.f, 0.f, 0.f};
            accV[i][j] = (f32x4){0.f, 0.f, 0.f, 0.f};
            accR[i][j] = (f32x4){0.f, 0.f, 0.f, 0.f};
        }

#define SG_A(bo, tau)  do { GLLDS(A  + offA0 + (tau) * 64, As  + (bo) + dst0); \
                            GLLDS(A  + offA1 + (tau) * 64, As  + (bo) + dst1); } while (0)
#define SG_BK(bo, tau) do { GLLDS(Wk + offB0 + (tau) * 64, Bks + (bo) + dst0); \
                            GLLDS(Wk + offB1 + (tau) * 64, Bks + (bo) + dst1); } while (0)
#define SG_BV(bo, tau) do { GLLDS(Wv + offB0 + (tau) * 64, Bvs + (bo) + dst0); \
                            GLLDS(Wv + offB1 + (tau) * 64, Bvs + (bo) + dst1); } while (0)
#define SG_BR(bo, tau) do { GLLDS(Wr + offB0 + (tau) * 64, Brs + (bo) + dst0); \
                            GLLDS(Wr + offB1 + (tau) * 64, Brs + (bo) + dst1); } while (0)
#define RD_AALL(CUR)                                                          \
    _Pragma("unroll") for (int mi = 0; mi < 4; ++mi)                          \
    _Pragma("unroll") for (int ks = 0; ks < 2; ++ks)                          \
        aR[mi][ks] = *(const bf16x8*)&As[(CUR) + aB[mi] + gx[ks]];
#define RD_B(ARR, CUR)                                                        \
    _Pragma("unroll") for (int nj = 0; nj < 2; ++nj)                          \
    _Pragma("unroll") for (int ks = 0; ks < 2; ++ks)                          \
        bR[nj][ks] = *(const bf16x8*)&ARR[(CUR) + bB[nj] + gx[ks]];
#define MFMA16(ACC)                                                           \
    __builtin_amdgcn_s_setprio(1);                                            \
    _Pragma("unroll") for (int mi = 0; mi < 4; ++mi)                          \
    _Pragma("unroll") for (int nj = 0; nj < 2; ++nj)                          \
    _Pragma("unroll") for (int ks = 0; ks < 2; ++ks)                          \
        ACC[mi][nj] = __builtin_amdgcn_mfma_f32_16x16x32_bf16(                \
            aR[mi][ks], bR[nj][ks], ACC[mi][nj], 0, 0, 0);                    \
    __builtin_amdgcn_s_setprio(0);

    SG_A(0, 0); SG_BK(0, 0); SG_BV(0, 0); SG_BR(0, 0);
    asm volatile("s_waitcnt vmcnt(4)" ::: "memory");
    BAR();

#pragma unroll 1
    for (int t = 0; t < 15; ++t) {
        const int cur = (t & 1) << 13;
        const int nxt = cur ^ 8192;
        bf16x8 aR[4][2], bR[2][2];

        RD_AALL(cur); RD_B(Bks, cur);
        SG_A(nxt, t + 1); SG_BK(nxt, t + 1);
        BAR(); MFMA16(accK);
        asm volatile("s_waitcnt vmcnt(6)" ::: "memory");
        BAR();

        RD_B(Bvs, cur);
        SG_BV(nxt, t + 1);
        BAR(); MFMA16(accV);
        asm volatile("s_waitcnt vmcnt(6)" ::: "memory");
        BAR();

        RD_B(Brs, cur);
        SG_BR(nxt, t + 1);
        BAR(); MFMA16(accR);
        asm volatile("s_waitcnt vmcnt(4)" ::: "memory");
        BAR();
    }
    {
        const int cur = 8192;
        bf16x8 aR[4][2], bR[2][2];
        RD_AALL(cur); RD_B(Bks, cur);
        BAR(); MFMA16(accK);
        asm volatile("s_waitcnt vmcnt(2)" ::: "memory");
        BAR();
        RD_B(Bvs, cur);
        BAR(); MFMA16(accV);
        asm volatile("s_waitcnt vmcnt(0)" ::: "memory");
        BAR();
        RD_B(Brs, cur);
        MFMA16(accR);
    }
#undef SG_A
#undef SG_BK
#undef SG_BV
#undef SG_BR
#undef RD_AALL
#undef RD_B
#undef MFMA16

    const int orow0 = brow + wrow * 64;
    const int ocol0 = bcol + wcol * 32;
    const int rbase = q * 4;
    const int b = brow >> 12;
    float dcol[2][4];
#pragma unroll
    for (int ni = 0; ni < 2; ++ni)
#pragma unroll
        for (int d = 0; d < 4; ++d)
            dcol[ni][d] = dec[b * (D_ * H_) + d * H_ + (ocol0 + ni * 16 + l15)];
#pragma unroll
    for (int mi = 0; mi < 4; ++mi)
#pragma unroll
        for (int j = 0; j < 4; ++j) {
            const int r = orow0 + mi * 16 + rbase + j;
            const f32x4 lw = *(const f32x4*)(lgw + (size_t)r * 4);
            const float wsum = lw[0] + lw[1] + lw[2] + lw[3];
#pragma unroll
            for (int ni = 0; ni < 2; ++ni) {
                const size_t idx = (size_t)r * 1024 + (ocol0 + ni * 16 + l15);
                const float kvf = b2f(f2b(accV[mi][ni][j] * b2f(f2b(accK[mi][ni][j]))));
                const float rv  = 1.0f / (1.0f + __expf(-accR[mi][ni][j]));
                const float w   = lw[0] * dcol[ni][0] + lw[1] * dcol[ni][1]
                                + lw[2] * dcol[ni][2] + lw[3] * dcol[ni][3]
                                + wsum * kvf;
                Co[idx] = f2b(rv * w);
            }
        }
}

// ---------------------------------------------------------------------------
// o-GEMM: R8 reads/phases/MFMA verbatim; ONLY stage placement + waits changed:
// P1: stage B01(t+1); P2: stage B23(t+1); P3: stage A0,A2(t+1);
// P4: stage A1,A3(t+1); tile-end vmcnt(2); P2-end vmcnt(4).
// FIFO {B0,B1,B2,B3,A0,A2,A1,A3}: next-P1 needs pos1-6 (1.5-3.5 phases old),
// A1,A3 (pos7,8) needed at next-P3 (2.5 phases old). No drain-0 in loop.
// ---------------------------------------------------------------------------
__global__ __launch_bounds__(512, 2) void gemm_o(
    const unsigned short* __restrict__ A,
    const unsigned short* __restrict__ Wt,
    float* __restrict__ outf)
{
    __shared__ __align__(16) unsigned short As[2 * 256 * 64];
    __shared__ __align__(16) unsigned short Bs[2 * 256 * 64];

    const int tid  = threadIdx.x;
    const int wid  = tid >> 6;
    const int lane = tid & 63;
    const int l15  = lane & 15;
    const int l7   = lane & 7;
    const int wrow = wid >> 2;
    const int wcol = wid & 3;
    const int brow = blockIdx.x * 256;
    const int bcol = blockIdx.y * 256;

    int offA[4], offB[4], dst[4];
#pragma unroll
    for (int i = 0; i < 4; ++i) {
        const int G   = i * 512 + tid;
        const int row = G >> 3;
        const int cg  = (G & 7) ^ (row & 7);
        offA[i] = (brow + row) * 1024 + cg * 8;
        offB[i] = (bcol + row) * 1024 + cg * 8;
        dst[i]  = G * 8;
    }

    int aB[8], bB[4], gx[2];
#pragma unroll
    for (int ks = 0; ks < 2; ++ks) gx[ks] = ((ks * 4 + (lane >> 4)) ^ l7) * 8;
#pragma unroll
    for (int mi = 0; mi < 8; ++mi) aB[mi] = (wrow * 128 + mi * 16 + l15) * 64;
#pragma unroll
    for (int ni = 0; ni < 4; ++ni) bB[ni] = (wcol * 64 + ni * 16 + l15) * 64;

    f32x4 acc[8][4];
#pragma unroll
    for (int i = 0; i < 8; ++i)
#pragma unroll
        for (int j = 0; j < 4; ++j)
            acc[i][j] = (f32x4){0.f, 0.f, 0.f, 0.f};

    // prologue: tile 0 in steady-state FIFO order {B0,B1,B2,B3,A0,A2,A1,A3}
    GLLDS(Wt + offB[0], Bs + dst[0]);
    GLLDS(Wt + offB[1], Bs + dst[1]);
    GLLDS(Wt + offB[2], Bs + dst[2]);
    GLLDS(Wt + offB[3], Bs + dst[3]);
    GLLDS(A  + offA[0], As + dst[0]);
    GLLDS(A  + offA[2], As + dst[2]);
    GLLDS(A  + offA[1], As + dst[1]);
    GLLDS(A  + offA[3], As + dst[3]);
    asm volatile("s_waitcnt vmcnt(2)" ::: "memory");   // pos1-6 landed
    BAR();

#pragma unroll 1
    for (int t = 0; t < 16; ++t) {
        const int cur = (t & 1) * 16384;
        const int nxt = 16384 - cur;
        const int kk  = (t + 1) * 64;
        const bool st = (t < 15);
        bf16x8 aR[4][2], bR[4][2];

        // P1: rd a(mi0-3)+b(n01); stage B01(t+1)
#pragma unroll
        for (int mi = 0; mi < 4; ++mi)
#pragma unroll
            for (int ks = 0; ks < 2; ++ks)
                aR[mi][ks] = *(const bf16x8*)&As[cur + aB[mi] + gx[ks]];
#pragma unroll
        for (int ni = 0; ni < 2; ++ni)
#pragma unroll
            for (int ks = 0; ks < 2; ++ks)
                bR[ni][ks] = *(const bf16x8*)&Bs[cur + bB[ni] + gx[ks]];
        if (st) {
            GLLDS(Wt + offB[0] + kk, Bs + nxt + dst[0]);
            GLLDS(Wt + offB[1] + kk, Bs + nxt + dst[1]);
        }
        BAR();
        __builtin_amdgcn_s_setprio(1);
#pragma unroll
        for (int mi = 0; mi < 4; ++mi)
#pragma unroll
            for (int ni = 0; ni < 2; ++ni)
#pragma unroll
                for (int ks = 0; ks < 2; ++ks)
                    acc[mi][ni] = __builtin_amdgcn_mfma_f32_16x16x32_bf16(
                        aR[mi][ks], bR[ni][ks], acc[mi][ni], 0, 0, 0);
        __builtin_amdgcn_s_setprio(0);
        BAR();

        // P2: rd b(n23); stage B23(t+1); wait A1,A3(t) (issued t-1 P4)
#pragma unroll
        for (int ni = 2; ni < 4; ++ni)
#pragma unroll
            for (int ks = 0; ks < 2; ++ks)
                bR[ni][ks] = *(const bf16x8*)&Bs[cur + bB[ni] + gx[ks]];
        if (st) {
            GLLDS(Wt + offB[2] + kk, Bs + nxt + dst[2]);
            GLLDS(Wt + offB[3] + kk, Bs + nxt + dst[3]);
        }
        BAR();
        __builtin_amdgcn_s_setprio(1);
#pragma unroll
        for (int mi = 0; mi < 4; ++mi)
#pragma unroll
            for (int ni = 2; ni < 4; ++ni)
#pragma unroll
                for (int ks = 0; ks < 2; ++ks)
                    acc[mi][ni] = __builtin_amdgcn_mfma_f32_16x16x32_bf16(
                        aR[mi][ks], bR[ni][ks], acc[mi][ni], 0, 0, 0);
        __builtin_amdgcn_s_setprio(0);
        if (st) asm volatile("s_waitcnt vmcnt(4)" ::: "memory");
        else    asm volatile("s_waitcnt vmcnt(0)" ::: "memory");
        BAR();

        // P3: rd a(mi4-7); stage A0,A2(t+1)
#pragma unroll
        for (int mi = 0; mi < 4; ++mi)
#pragma unroll
            for (int ks = 0; ks < 2; ++ks)
                aR[mi][ks] = *(const bf16x8*)&As[cur + aB[4 + mi] + gx[ks]];
        if (st) {
            GLLDS(A + offA[0] + kk, As + nxt + dst[0]);
            GLLDS(A + offA[2] + kk, As + nxt + dst[2]);
        }
        BAR();
        __builtin_amdgcn_s_setprio(1);
#pragma unroll
        for (int mi = 0; mi < 4; ++mi)
#pragma unroll
            for (int ni = 2; ni < 4; ++ni)
#pragma unroll
                for (int ks = 0; ks < 2; ++ks)
                    acc[4 + mi][ni] = __builtin_amdgcn_mfma_f32_16x16x32_bf16(
                        aR[mi][ks], bR[ni][ks], acc[4 + mi][ni], 0, 0, 0);
        __builtin_amdgcn_s_setprio(0);
        BAR();

        // P4: stage A1,A3(t+1); tile-end counted wait vmcnt(2)
        if (st) {
            GLLDS(A + offA[1] + kk, As + nxt + dst[1]);
            GLLDS(A + offA[3] + kk, As + nxt + dst[3]);
        }
        __builtin_amdgcn_s_setprio(1);
#pragma unroll
        for (int mi = 0; mi < 4; ++mi)
#pragma unroll
            for (int ni = 0; ni < 2; ++ni)
#pragma unroll
                for (int ks = 0; ks < 2; ++ks)
                    acc[4 + mi][ni] = __builtin_amdgcn_mfma_f32_16x16x32_bf16(
                        aR[mi][ks], bR[ni][ks], acc[4 + mi][ni], 0, 0, 0);
        __builtin_amdgcn_s_setprio(0);
        if (st) {
            asm volatile("s_waitcnt vmcnt(2)" ::: "memory");
            BAR();
        }
    }

    const int orow0 = brow + wrow * 128;
    const int ocol0 = bcol + wcol * 64;
    const int rbase = (lane >> 4) * 4;
#pragma unroll
    for (int mi = 0; mi < 8; ++mi)
#pragma unroll
        for (int j = 0; j < 4; ++j) {
            const size_t r = (size_t)(orow0 + mi * 16 + rbase + j);
#pragma unroll
            for (int ni = 0; ni < 4; ++ni)
                outf[r * 1024 + (ocol0 + ni * 16 + l15)] = acc[mi][ni][j];
        }
}

// ---------------------------------------------------------------------------
extern "C" void kernel_launch(void* const* d_in, const int* in_sizes, int n_in,
                              void* d_out, int out_size, void* d_ws, size_t ws_size,
                              hipStream_t stream)
{
    const float* x   = (const float*)d_in[0];
    const float* st  = (const float*)d_in[1];
    const float* tdm = (const float*)d_in[2];
    const float* Wl  = (const float*)d_in[3];
    const float* bl  = (const float*)d_in[4];
    const float* Wv  = (const float*)d_in[5];
    const float* Wk  = (const float*)d_in[6];
    const float* Wr  = (const float*)d_in[7];
    const float* Wo  = (const float*)d_in[8];
    float* out = (float*)d_out;                    // f32 output

    char* ws = (char*)d_ws;
    unsigned short* buf  = (unsigned short*)(ws + WS_BUF);   // o
    unsigned short* wk_b = (unsigned short*)(ws + WS_WK);    // [4][H][H]: k,v,r,o
    unsigned short* wv_b = wk_b + 1 * (H_ * H_);
    unsigned short* wr_b = wk_b + 2 * (H_ * H_);
    unsigned short* wo_b = wk_b + 3 * (H_ * H_);
    float* lgw = (float*)(ws + WS_LGW);
    float* dec = (float*)(ws + WS_DEC);

    // bf16 x scratch inside d_out's f32 output-0 region; final GEMM
    // fully overwrites it afterwards.
    unsigned short* xb = (unsigned short*)out;

    // small kernels
    logcvt_k<<<M_ / 4, 256, 0, stream>>>(x, Wl, bl, lgw, xb);
    newstate_k<<<(B_ * H_) / 4, 256, 0, stream>>>(x, Wk, Wv, st, tdm, dec, out + OUT_MAIN);
    cvtw_k<<<dim3(1024, 4), 256, 0, stream>>>(Wk, Wv, Wr, Wo, wk_b);

    // buf = o = sigmoid(x@Wr^T) * (lw.dec + wsum*(x@Wk^T * x@Wv^T))
    gemm_kvr<<<dim3(8, 128), 512, 0, stream>>>(
        xb, wk_b, wv_b, wr_b, buf, lgw, dec);

    // out = f32(o @ Wo^T)
    gemm_o<<<dim3(M_ / 256, H_ / 256), 512, 0, stream>>>(buf, wo_b, out);
}